// Round 16
// baseline (334.480 us; speedup 1.0000x reference)
//
#include <hip/hip_runtime.h>
#include <hip/hip_bf16.h>
#include <math.h>

#define NH 12
#define HD 64
#define ED 768
#define CD 512
#define FD 3072
#define BB 8
#define SS 1024
#define TT 256
#define LN_EPS 1e-5f
#define ATT_SCALE 0.125f
#define QSC_LOG2E 0.1803368801111204f  // ATT_SCALE * log2(e): softmax in base-2
#define P_M0 11.55f                    // fixed softmax max: |q||k|*scale*log2e < 11.545
#define TOT_R 6291456                  // B*NH*SS*HD elements per head-tensor region

typedef __attribute__((ext_vector_type(8))) __bf16 bf16x8;
typedef __attribute__((ext_vector_type(4))) __bf16 bf16x4;
typedef __attribute__((ext_vector_type(4))) float f32x4;

typedef const __attribute__((address_space(1))) void* gas1_t;
typedef __attribute__((address_space(3))) void* las3_t;

__device__ __forceinline__ void gl16(const void* g, void* l) {
  // async global->LDS, 16B per lane; LDS dest is wave-linear (base+lane*16)
  __builtin_amdgcn_global_load_lds((gas1_t)g, (las3_t)l, 16, 0, 0);
}

__device__ __forceinline__ ushort f2bf(float f) {
  union { __bf16 b; ushort u; } c;
  c.b = (__bf16)f;  // fptrunc RNE -> v_cvt_pk_bf16_f32 (compiler pairs them)
  return c.u;
}
__device__ __forceinline__ float bf2f(ushort u) {
  return __uint_as_float((unsigned)u << 16);
}

// fast GELU: x*sigmoid(1.5958(x+0.044715x^3)) via native exp2/rcp.
__device__ __forceinline__ float gelu_fast(float c) {
  const float x2 = c * c;
  const float ex = __builtin_amdgcn_exp2f(c * (-2.3022084f - 0.10294325f * x2));
  return c * __builtin_amdgcn_rcpf(1.0f + ex);
}

// Swizzled MFMA fragment read from a [rows][64]-ushort tile (128B rows).
__device__ __forceinline__ bf16x8 frag64(const ushort (*T)[64], int row, int q8) {
  return *(const bf16x8*)((const char*)T + row * 128 + ((q8 ^ (row & 7)) << 4));
}

// Swizzled MFMA fragment read from a [rows][32]-ushort tile (64B rows).
// Quantum q of row r lives at byte r*64 + ((q^((r>>1)&3))<<4) -> a 16-row
// fragment read covers all 8 (parity x quantum) slots with 2 lanes each.
__device__ __forceinline__ bf16x8 frag32(const ushort (*T)[32], int row, int g) {
  return *(const bf16x8*)((const char*)T + row * 64 + ((g ^ ((row >> 1) & 3)) << 4));
}

// ---------------------------------------------------------------------------
// Fused conversion kernel: jobs 0..9 = W[K,N] fp32 -> WT[N,K] bf16 transposes,
// jobs 10..11 = flat fp32 -> bf16 converts. One launch for everything.
// ---------------------------------------------------------------------------
struct CvtPack {
  const float* src[12];
  ushort* dst[12];
  int kd[12];   // transpose: Kd ; flat: n4 element count
  int nd[12];   // transpose: Nd ; flat: 0
  int off[13];  // prefix block offsets
};

__global__ __launch_bounds__(256) void cvt_all(CvtPack P) {
  __shared__ float t[32][33];
  const int flat = blockIdx.x;
  int j = 0;
  while (j < 11 && flat >= P.off[j + 1]) ++j;
  const int rel = flat - P.off[j];
  if (P.nd[j] == 0) {  // flat convert
    const int i = rel * 256 + threadIdx.x;
    if (i < P.kd[j]) {
      float4 v = ((const float4*)P.src[j])[i];
      ((ushort4*)P.dst[j])[i] =
          make_ushort4(f2bf(v.x), f2bf(v.y), f2bf(v.z), f2bf(v.w));
    }
    return;
  }
  const int Kd = P.kd[j], Nd = P.nd[j];
  const int ntx = Nd >> 5;
  const int n0 = (rel % ntx) * 32, k0 = (rel / ntx) * 32;
  const float* W = P.src[j];
  ushort* WT = P.dst[j];
  const int tx = threadIdx.x & 31, ty = threadIdx.x >> 5;  // ty 0..7
#pragma unroll
  for (int r = 0; r < 4; ++r)
    t[ty + 8 * r][tx] = W[(size_t)(k0 + ty + 8 * r) * Nd + n0 + tx];
  __syncthreads();
#pragma unroll
  for (int r = 0; r < 4; ++r)
    WT[(size_t)(n0 + ty + 8 * r) * Kd + k0 + tx] = f2bf(t[tx][ty + 8 * r]);
}

// ---------------------------------------------------------------------------
// bf16 MFMA GEMM: C[M,N] = A[M,K] @ Wt[N,K]^T (+bias).
// Tile 128x128, BK=64, 256 thr = 4 waves in 2x2, each wave 64x64 = 4x4 frags.
// PIPELINED (2-phase): double-buffered LDS, one barrier per K-step.
// MODE 0: fp32 out + bias. MODE 1: bf16 + bias + fast GELU. MODE 3: bf16 +
// bias. MODE 2: heads bf16 out, fused per-head LN (t_q folds QSC_LOG2E),
// t_v written TRANSPOSED [B,H,D,Stok].
// ---------------------------------------------------------------------------
template <int MODE>
__global__ __launch_bounds__(256) void mfma_gemm(
    const ushort* __restrict__ A, const ushort* __restrict__ Wt,
    const float* __restrict__ bias, void* __restrict__ outp,
    int M, int N, int K, int sshift,
    const float* __restrict__ qg, const float* __restrict__ qb,
    const float* __restrict__ kg, const float* __restrict__ kb,
    int t_q, int t_k, int t_v) {
  __shared__ ushort As[2][128][64];  // 2 x 16 KB, 128B rows, swizzled quanta
  __shared__ ushort Bs[2][128][64];
  const int tid = threadIdx.x;
  const int m0 = blockIdx.x * 128, n0 = blockIdx.y * 128;
  const int lane = tid & 63;
  const int wr = ((tid >> 6) >> 1) * 64, wc = ((tid >> 6) & 1) * 64;
  const int l15 = lane & 15, g = lane >> 4;
  f32x4 acc[4][4] = {};

  auto stage = [&](int bi, int kt) {
#pragma unroll
    for (int p = 0; p < 4; ++p) {
      const int flat = p * 256 + tid;          // 16B-quantum index, wave-linear
      const int row = flat >> 3, q8 = flat & 7;
      const int kc = 8 * (q8 ^ (row & 7));     // inverse-swizzled source col
      gl16(&A[(size_t)(m0 + row) * K + kt + kc], (char*)As[bi] + flat * 16);
      gl16(&Wt[(size_t)(n0 + row) * K + kt + kc], (char*)Bs[bi] + flat * 16);
    }
  };

  stage(0, 0);
  __syncthreads();  // drains chunk-0 DMA (implicit vmcnt(0))
  int cur = 0;
  for (int kt = 0; kt < K; kt += 64) {
    if (kt + 64 < K) stage(cur ^ 1, kt + 64);  // in flight under compute
#pragma unroll
    for (int h = 0; h < 2; ++h) {
      bf16x8 af[4], bfv[4];
#pragma unroll
      for (int i = 0; i < 4; ++i) {
        af[i] = frag64(As[cur], wr + i * 16 + l15, 4 * h + g);
        bfv[i] = frag64(Bs[cur], wc + i * 16 + l15, 4 * h + g);
      }
#pragma unroll
      for (int i = 0; i < 4; ++i)
#pragma unroll
        for (int j = 0; j < 4; ++j)
          acc[i][j] = __builtin_amdgcn_mfma_f32_16x16x32_bf16(af[i], bfv[j],
                                                              acc[i][j], 0, 0, 0);
    }
    __syncthreads();  // next buffer complete; all reads of cur done
    cur ^= 1;
  }

  if (MODE == 2) {
    ushort* out = (ushort*)outp;
    const int Stok = 1 << sshift, smask = Stok - 1;
    const int ht0 = (n0 + wc) >> 6;            // wave-uniform head-column
    const int t = ht0 / NH, h = ht0 - t * NH;
    const bool isq = (t == t_q), isk = (t == t_k);
    if (isq || isk) {  // fused per-head LayerNorm over the wave's 64 cols
      const float* gg = isq ? qg : kg;
      const float* bb = isq ? qb : kb;
      const float osc = isq ? QSC_LOG2E : 1.0f;
      float gv[4], bv[4];
#pragma unroll
      for (int j = 0; j < 4; ++j) {
        gv[j] = gg[j * 16 + l15];
        bv[j] = bb[j * 16 + l15];
      }
#pragma unroll
      for (int i = 0; i < 4; ++i)
#pragma unroll
        for (int r = 0; r < 4; ++r) {
          float s = acc[i][0][r] + acc[i][1][r] + acc[i][2][r] + acc[i][3][r];
          float sq = acc[i][0][r] * acc[i][0][r] + acc[i][1][r] * acc[i][1][r] +
                     acc[i][2][r] * acc[i][2][r] + acc[i][3][r] * acc[i][3][r];
          s += __shfl_xor(s, 1);  sq += __shfl_xor(sq, 1);
          s += __shfl_xor(s, 2);  sq += __shfl_xor(sq, 2);
          s += __shfl_xor(s, 4);  sq += __shfl_xor(sq, 4);
          s += __shfl_xor(s, 8);  sq += __shfl_xor(sq, 8);
          const float mean = s * (1.0f / 64.0f);
          const float var = sq * (1.0f / 64.0f) - mean * mean;
          const float rs = rsqrtf(fmaxf(var, 0.0f) + LN_EPS);
#pragma unroll
          for (int j = 0; j < 4; ++j)
            acc[i][j][r] = ((acc[i][j][r] - mean) * rs * gv[j] + bv[j]) * osc;
        }
    }
    if (t == t_v) {  // transposed V^T output: [B,H,D=64,Stok], 4-s packs
#pragma unroll
      for (int i = 0; i < 4; ++i) {
        const int row = m0 + wr + i * 16 + g * 4;  // 4 consecutive tokens
        const int b = row >> sshift, s2 = row & smask;
        ushort* obase =
            out + (size_t)t * TOT_R + (((size_t)b * NH + h) * 64) * Stok + s2;
#pragma unroll
        for (int j = 0; j < 4; ++j) {
          const int d = j * 16 + l15;
          ushort4 pk = make_ushort4(f2bf(acc[i][j][0]), f2bf(acc[i][j][1]),
                                    f2bf(acc[i][j][2]), f2bf(acc[i][j][3]));
          *(ushort4*)&obase[(size_t)d * Stok] = pk;
        }
      }
    } else {
#pragma unroll
      for (int i = 0; i < 4; ++i)
#pragma unroll
        for (int r = 0; r < 4; ++r) {
          const int row = m0 + wr + i * 16 + g * 4 + r;
          const int b = row >> sshift, s2 = row & smask;
          ushort* orow =
              out + (size_t)t * TOT_R + (((size_t)b * NH + h) * Stok + s2) * 64;
#pragma unroll
          for (int j = 0; j < 4; ++j) orow[j * 16 + l15] = f2bf(acc[i][j][r]);
        }
    }
  } else {
#pragma unroll
    for (int i = 0; i < 4; ++i) {
#pragma unroll
      for (int j = 0; j < 4; ++j) {
        const int gc = n0 + wc + j * 16 + l15;
        const float bv = bias ? bias[gc] : 0.0f;
#pragma unroll
        for (int r = 0; r < 4; ++r) {
          const int row = m0 + wr + i * 16 + g * 4 + r;
          float c = acc[i][j][r] + bv;
          if (MODE == 1) {
            c = gelu_fast(c);
            ((ushort*)outp)[(size_t)row * N + gc] = f2bf(c);
          } else if (MODE == 3) {
            ((ushort*)outp)[(size_t)row * N + gc] = f2bf(c);
          } else {
            ((float*)outp)[(size_t)row * N + gc] = c;
          }
        }
      }
    }
  }
}

// ---------------------------------------------------------------------------
// 8-wave 256x256 deep-pipelined GEMM (T3+T4 regime): C = GELU(A@Wt^T + bias),
// bf16 out. BK=32, THREE-buffered LDS (96 KB), block = 512 (8 waves, 2Mx4N;
// wave tile 128x64, acc 8x4 f32x4). Per K-step: counted s_waitcnt vmcnt(4)
// (step t+1's 4 loads stay in flight — never drains to 0 mid-loop) + top
// barrier (buf t landed for all waves), then TWO fine phases, each
// {ds_read subtile || issue 2 stage-chunks of step t+2 -> barrier ->
//  setprio(1) 16 MFMA setprio(0) -> barrier}.
// Race-safety: step t's stage targets buf (t+2)%3 == buf read at step t-1,
// whose reads all completed before step t's top barrier; vmem retires
// in-order so vmcnt(4) proves buf t's DMA landed.
// Swizzle: frag32 pair (q^=(row>>1)&3 on 64B rows), proven in R10-R13.
// ---------------------------------------------------------------------------
__global__ __launch_bounds__(512, 2) void mfma_gemm8(
    const ushort* __restrict__ A, const ushort* __restrict__ Wt,
    const float* __restrict__ bias, ushort* __restrict__ outp, int N, int K) {
  __shared__ ushort As[3][256][32];  // 3 x 16 KB
  __shared__ ushort Bs[3][256][32];  // 3 x 16 KB
  const int tid = threadIdx.x;
  const int m0 = blockIdx.x * 256, n0 = blockIdx.y * 256;
  const int lane = tid & 63;
  const int w = tid >> 6;
  const int wm = w >> 2, wn = w & 3;          // 2 x 4 wave grid
  const int l15 = lane & 15, g = lane >> 4;
  const int rbase = wm * 128;                 // wave A-row base (in tile)
  const int cbase = wn * 64;                  // wave B-col base (in tile)
  f32x4 acc[8][4] = {};

  // stage chunk c of K-step kt into buffer bi. c 0..1: A halves, 2..3: B
  // halves; each chunk = 512 16B-quanta = one gl16 per thread.
  auto stagec = [&](int bi, int kt, int c) {
    const int fq = (c & 1) * 512 + tid;
    const int row = fq >> 2, q = fq & 3;
    const int kc = 8 * (q ^ ((row >> 1) & 3));  // inverse-swizzled source
    if (c < 2)
      gl16(&A[(size_t)(m0 + row) * K + kt + kc], (char*)As[bi] + fq * 16);
    else
      gl16(&Wt[(size_t)(n0 + row) * K + kt + kc], (char*)Bs[bi] + fq * 16);
  };

  const int nst = K >> 5;
  // prologue: 2-deep prefetch
#pragma unroll
  for (int c = 0; c < 4; ++c) stagec(0, 0, c);
#pragma unroll
  for (int c = 0; c < 4; ++c) stagec(1, 32, c);

  int bt = 0;
  for (int t = 0; t < nst; ++t) {
    // counted wait: step t+1's 4 loads may remain outstanding; step t's
    // (older, in-order) must have retired.
    if (t < nst - 1) asm volatile("s_waitcnt vmcnt(4)" ::: "memory");
    else             asm volatile("s_waitcnt vmcnt(0)" ::: "memory");
    __builtin_amdgcn_s_barrier();   // buf bt landed for ALL waves
    int b2 = bt + 2; if (b2 >= 3) b2 -= 3;
    const bool pf = (t + 2 < nst);
    const int kt2 = (t + 2) * 32;

    bf16x8 af[8], bf[4];
    // ---- phase 0: all m-frags x n-cols 0..31 ----
#pragma unroll
    for (int i = 0; i < 8; ++i) af[i] = frag32(As[bt], rbase + i * 16 + l15, g);
    bf[0] = frag32(Bs[bt], cbase + l15, g);
    bf[1] = frag32(Bs[bt], cbase + 16 + l15, g);
    if (pf) { stagec(b2, kt2, 0); stagec(b2, kt2, 1); }
    __builtin_amdgcn_s_barrier();
    __builtin_amdgcn_s_setprio(1);
#pragma unroll
    for (int i = 0; i < 8; ++i) {
      acc[i][0] = __builtin_amdgcn_mfma_f32_16x16x32_bf16(af[i], bf[0], acc[i][0], 0, 0, 0);
      acc[i][1] = __builtin_amdgcn_mfma_f32_16x16x32_bf16(af[i], bf[1], acc[i][1], 0, 0, 0);
    }
    __builtin_amdgcn_s_setprio(0);
    __builtin_amdgcn_s_barrier();
    // ---- phase 1: all m-frags x n-cols 32..63 ----
    bf[2] = frag32(Bs[bt], cbase + 32 + l15, g);
    bf[3] = frag32(Bs[bt], cbase + 48 + l15, g);
    if (pf) { stagec(b2, kt2, 2); stagec(b2, kt2, 3); }
    __builtin_amdgcn_s_barrier();
    __builtin_amdgcn_s_setprio(1);
#pragma unroll
    for (int i = 0; i < 8; ++i) {
      acc[i][2] = __builtin_amdgcn_mfma_f32_16x16x32_bf16(af[i], bf[2], acc[i][2], 0, 0, 0);
      acc[i][3] = __builtin_amdgcn_mfma_f32_16x16x32_bf16(af[i], bf[3], acc[i][3], 0, 0, 0);
    }
    __builtin_amdgcn_s_setprio(0);
    __builtin_amdgcn_s_barrier();
    if (++bt == 3) bt = 0;
  }

  // ---- epilogue: bias + fast GELU + bf16 store ----
#pragma unroll
  for (int i = 0; i < 8; ++i) {
#pragma unroll
    for (int j = 0; j < 4; ++j) {
      const int gc = n0 + cbase + j * 16 + l15;
      const float bv = bias[gc];
#pragma unroll
      for (int r = 0; r < 4; ++r) {
        const int row = m0 + rbase + i * 16 + g * 4 + r;
        outp[(size_t)row * N + gc] = f2bf(gelu_fast(acc[i][j][r] + bv));
      }
    }
  }
}

// ---------------------------------------------------------------------------
// Dual-job MODE-2 GEMM: fuses CA-Q and CA-KV projections into one dispatch.
// flat blocks [0,192): CAKV (M=2048, N=1536, K=512); [192,576): CAQ.
// ---------------------------------------------------------------------------
__global__ __launch_bounds__(256) void mfma_gemm_ca(
    const ushort* __restrict__ A0, const ushort* __restrict__ Wt0,
    void* __restrict__ out0,
    const ushort* __restrict__ A1, const ushort* __restrict__ Wt1,
    void* __restrict__ out1,
    const float* __restrict__ qg, const float* __restrict__ qb,
    const float* __restrict__ kg, const float* __restrict__ kb) {
  __shared__ ushort As[2][128][64];
  __shared__ ushort Bs[2][128][64];
  const int tid = threadIdx.x;
  const int fb = blockIdx.x;
  const ushort* A;
  const ushort* Wt;
  ushort* out;
  int m0, n0, K, sshift, t_q, t_k, t_v;
  if (fb < 192) {  // job B: CAKV
    A = A1; Wt = Wt1; out = (ushort*)out1;
    K = CD; sshift = 8;
    m0 = (fb & 15) * 128; n0 = (fb >> 4) * 128;
    t_q = -1; t_k = 0; t_v = 1;
  } else {         // job A: CAQ
    const int id = fb - 192;
    A = A0; Wt = Wt0; out = (ushort*)out0;
    K = ED; sshift = 10;
    m0 = (id & 63) * 128; n0 = (id >> 6) * 128;
    t_q = 0; t_k = -1; t_v = -1;
  }
  const int lane = tid & 63;
  const int wr = ((tid >> 6) >> 1) * 64, wc = ((tid >> 6) & 1) * 64;
  const int l15 = lane & 15, g = lane >> 4;
  f32x4 acc[4][4] = {};

  auto stage = [&](int bi, int kt) {
#pragma unroll
    for (int p = 0; p < 4; ++p) {
      const int flat = p * 256 + tid;
      const int row = flat >> 3, q8 = flat & 7;
      const int kc = 8 * (q8 ^ (row & 7));
      gl16(&A[(size_t)(m0 + row) * K + kt + kc], (char*)As[bi] + flat * 16);
      gl16(&Wt[(size_t)(n0 + row) * K + kt + kc], (char*)Bs[bi] + flat * 16);
    }
  };

  stage(0, 0);
  __syncthreads();
  int cur = 0;
  for (int kt = 0; kt < K; kt += 64) {
    if (kt + 64 < K) stage(cur ^ 1, kt + 64);
#pragma unroll
    for (int h = 0; h < 2; ++h) {
      bf16x8 af[4], bfv[4];
#pragma unroll
      for (int i = 0; i < 4; ++i) {
        af[i] = frag64(As[cur], wr + i * 16 + l15, 4 * h + g);
        bfv[i] = frag64(Bs[cur], wc + i * 16 + l15, 4 * h + g);
      }
#pragma unroll
      for (int i = 0; i < 4; ++i)
#pragma unroll
        for (int j = 0; j < 4; ++j)
          acc[i][j] = __builtin_amdgcn_mfma_f32_16x16x32_bf16(af[i], bfv[j],
                                                              acc[i][j], 0, 0, 0);
    }
    __syncthreads();
    cur ^= 1;
  }

  const int Stok = 1 << sshift, smask = Stok - 1;
  const int ht0 = (n0 + wc) >> 6;
  const int t = ht0 / NH, h = ht0 - t * NH;
  const bool isq = (t == t_q), isk = (t == t_k);
  if (isq || isk) {
    const float* gg = isq ? qg : kg;
    const float* bb = isq ? qb : kb;
    const float osc = isq ? QSC_LOG2E : 1.0f;
    float gv[4], bv[4];
#pragma unroll
    for (int j = 0; j < 4; ++j) {
      gv[j] = gg[j * 16 + l15];
      bv[j] = bb[j * 16 + l15];
    }
#pragma unroll
    for (int i = 0; i < 4; ++i)
#pragma unroll
      for (int r = 0; r < 4; ++r) {
        float s = acc[i][0][r] + acc[i][1][r] + acc[i][2][r] + acc[i][3][r];
        float sq = acc[i][0][r] * acc[i][0][r] + acc[i][1][r] * acc[i][1][r] +
                   acc[i][2][r] * acc[i][2][r] + acc[i][3][r] * acc[i][3][r];
        s += __shfl_xor(s, 1);  sq += __shfl_xor(sq, 1);
        s += __shfl_xor(s, 2);  sq += __shfl_xor(sq, 2);
        s += __shfl_xor(s, 4);  sq += __shfl_xor(sq, 4);
        s += __shfl_xor(s, 8);  sq += __shfl_xor(sq, 8);
        const float mean = s * (1.0f / 64.0f);
        const float var = sq * (1.0f / 64.0f) - mean * mean;
        const float rs = rsqrtf(fmaxf(var, 0.0f) + LN_EPS);
#pragma unroll
        for (int j = 0; j < 4; ++j)
          acc[i][j][r] = ((acc[i][j][r] - mean) * rs * gv[j] + bv[j]) * osc;
      }
  }
  if (t == t_v) {  // V^T output
#pragma unroll
    for (int i = 0; i < 4; ++i) {
      const int row = m0 + wr + i * 16 + g * 4;
      const int b = row >> sshift, s2 = row & smask;
      ushort* obase =
          out + (size_t)t * TOT_R + (((size_t)b * NH + h) * 64) * Stok + s2;
#pragma unroll
      for (int j = 0; j < 4; ++j) {
        const int d = j * 16 + l15;
        ushort4 pk = make_ushort4(f2bf(acc[i][j][0]), f2bf(acc[i][j][1]),
                                  f2bf(acc[i][j][2]), f2bf(acc[i][j][3]));
        *(ushort4*)&obase[(size_t)d * Stok] = pk;
      }
    }
  } else {
#pragma unroll
    for (int i = 0; i < 4; ++i)
#pragma unroll
      for (int r = 0; r < 4; ++r) {
        const int row = m0 + wr + i * 16 + g * 4 + r;
        const int b = row >> sshift, s2 = row & smask;
        ushort* orow =
            out + (size_t)t * TOT_R + (((size_t)b * NH + h) * Stok + s2) * 64;
#pragma unroll
        for (int j = 0; j < 4; ++j) orow[j * 16 + l15] = f2bf(acc[i][j][r]);
      }
  }
}

// ---------------------------------------------------------------------------
// MFMA flash attention v5 (unchanged).
// ---------------------------------------------------------------------------
__global__ __launch_bounds__(512) void flash_mfma(
    const ushort* __restrict__ Q, const ushort* __restrict__ K,
    const ushort* __restrict__ V, ushort* __restrict__ out, int Tkv) {
  __shared__ ushort Ks[2][64][64];   // 16 KB  [perm key][d]
  __shared__ ushort Vt[2][80][64];   // 20 KB  [d][key]; rows 64..79 = ones
  __shared__ ushort Ps[8][16][64];   // 16 KB  per-wave P tile [qrow][key]
  const int bh = blockIdx.x;
  const int b = bh / NH, h = bh % NH;
  const int qt = blockIdx.y;
  const int tid = threadIdx.x;
  const int w = tid >> 6, lane = tid & 63;
  const int l15 = lane & 15, g = lane >> 4;
  const int srow = tid >> 3;                       // LDS staging row
  const int q8s = tid & 7;
  const int skc = 8 * (q8s ^ (srow & 7));          // pre-swizzled source col
  const int kperm = 4 * (srow & 15) + (srow >> 4); // key held by LDS K-row srow

  const ushort* Qb = Q + ((size_t)bh * SS + qt * 256) * 64;
  const ushort* Kb = K + (size_t)bh * Tkv * 64;
  const ushort* Vb = V + (size_t)bh * Tkv * 64;    // V^T: [64][Tkv]

  // ---- issue DMA for chunk 0 (K permuted, V^T identity) ----
  gl16(&Kb[(size_t)kperm * 64 + skc], (char*)Ks[0] + tid * 16);
  gl16(&Vb[(size_t)srow * Tkv + skc], (char*)Vt[0] + tid * 16);

  // ones rows of Vt (both buffers), written once, untouched by DMA
  if (tid < 256) {
    const int bi = tid >> 7, rq = tid & 127;
    const uint4 ov = make_uint4(0x3F803F80u, 0x3F803F80u, 0x3F803F80u, 0x3F803F80u);
    *(uint4*)((char*)Vt[bi] + (64 + (rq >> 3)) * 128 + ((rq & 7) << 4)) = ov;
  }

  // ---- Q fragments straight to registers (2 subtiles x 2 k-octs) ----
  const ushort* qr0 = Qb + (w * 32 + l15) * 64;
  const bf16x8 qf00 = *(const bf16x8*)&qr0[g * 8];
  const bf16x8 qf01 = *(const bf16x8*)&qr0[32 + g * 8];
  const bf16x8 qf10 = *(const bf16x8*)&qr0[16 * 64 + g * 8];
  const bf16x8 qf11 = *(const bf16x8*)&qr0[16 * 64 + 32 + g * 8];
  __syncthreads();  // drains chunk-0 DMA + ones writes

  f32x4 oa[2][5] = {};
  // P-write byte offset: row g*4+r, cols 4*l15..4*l15+3 (one b64), swizzled
  const int pwofs = ((((l15 >> 1) ^ ((g * 4) & 7)) << 4) | ((l15 & 1) << 3));

  const int nch = Tkv >> 6;
  int cur = 0;
  for (int ci = 0; ci < nch; ++ci) {
    if (ci + 1 < nch) {  // DMA next chunk into other buffer; lands by barrier
      const int cnx = (ci + 1) << 6;
      const int nxt = cur ^ 1;
      gl16(&Kb[(size_t)(cnx + kperm) * 64 + skc], (char*)Ks[nxt] + tid * 16);
      gl16(&Vb[(size_t)srow * Tkv + cnx + skc], (char*)Vt[nxt] + tid * 16);
    }

    // ---- QK^T: 32q x 64k per wave (16 MFMA, kf shared across subtiles) ----
    f32x4 s[2][4] = {};
    __builtin_amdgcn_s_setprio(1);
#pragma unroll
    for (int kb = 0; kb < 4; ++kb) {
      bf16x8 kf0 = frag64(Ks[cur], kb * 16 + l15, g);
      bf16x8 kf1 = frag64(Ks[cur], kb * 16 + l15, 4 + g);
      s[0][kb] = __builtin_amdgcn_mfma_f32_16x16x32_bf16(qf00, kf0, s[0][kb], 0, 0, 0);
      s[0][kb] = __builtin_amdgcn_mfma_f32_16x16x32_bf16(qf01, kf1, s[0][kb], 0, 0, 0);
      s[1][kb] = __builtin_amdgcn_mfma_f32_16x16x32_bf16(qf10, kf0, s[1][kb], 0, 0, 0);
      s[1][kb] = __builtin_amdgcn_mfma_f32_16x16x32_bf16(qf11, kf1, s[1][kb], 0, 0, 0);
    }
    __builtin_amdgcn_s_setprio(0);

    // ---- softmax (fixed max) + packed P write + frag read, per subtile ----
    bf16x8 pfr[2][2];
#pragma unroll
    for (int sub = 0; sub < 2; ++sub) {
#pragma unroll
      for (int r = 0; r < 4; ++r) {
        bf16x4 pk;
#pragma unroll
        for (int kbv = 0; kbv < 4; ++kbv)
          pk[kbv] = (__bf16)__builtin_amdgcn_exp2f(s[sub][kbv][r] - P_M0);
        *(bf16x4*)((char*)Ps[w] + (g * 4 + r) * 128 + (pwofs ^ ((r & 7) << 4))) = pk;
      }
      pfr[sub][0] = frag64(Ps[w], l15, g);
      pfr[sub][1] = frag64(Ps[w], l15, 4 + g);
    }

    // ---- PV: O[32q x 80d] += P @ [V | 1] (20 MFMA; oa[.][4] = row-sums) ----
    __builtin_amdgcn_s_setprio(1);
#pragma unroll
    for (int jd = 0; jd < 5; ++jd) {
      const int d = jd * 16 + l15;
      bf16x8 vf0 = frag64(Vt[cur], d, g);
      bf16x8 vf1 = frag64(Vt[cur], d, 4 + g);
      oa[0][jd] = __builtin_amdgcn_mfma_f32_16x16x32_bf16(pfr[0][0], vf0, oa[0][jd], 0, 0, 0);
      oa[0][jd] = __builtin_amdgcn_mfma_f32_16x16x32_bf16(pfr[0][1], vf1, oa[0][jd], 0, 0, 0);
      oa[1][jd] = __builtin_amdgcn_mfma_f32_16x16x32_bf16(pfr[1][0], vf0, oa[1][jd], 0, 0, 0);
      oa[1][jd] = __builtin_amdgcn_mfma_f32_16x16x32_bf16(pfr[1][1], vf1, oa[1][jd], 0, 0, 0);
    }
    __builtin_amdgcn_s_setprio(0);

    __syncthreads();  // all reads of cur done; next-chunk DMA drained
    cur ^= 1;
  }

#pragma unroll
  for (int sub = 0; sub < 2; ++sub)
#pragma unroll
    for (int r = 0; r < 4; ++r) {
      const int row = qt * 256 + w * 32 + sub * 16 + g * 4 + r;
      const float inv = 1.0f / oa[sub][4][r];
#pragma unroll
      for (int jd = 0; jd < 4; ++jd)
        out[((size_t)b * SS + row) * ED + h * 64 + jd * 16 + l15] =
            f2bf(oa[sub][jd][r] * inv);
    }
}

// ---------------------------------------------------------------------------
// y = LN(a + alpha*bsrc); a is fp32 (af) OR bf16 (ab) — exactly one non-null.
// Write fp32 (outf) and/or bf16 (outb). Wave-per-row, no LDS, no barriers.
// ---------------------------------------------------------------------------
__global__ __launch_bounds__(256) void add_ln(
    const float* __restrict__ af, const ushort* __restrict__ ab,
    const float* __restrict__ bsrc, float alpha,
    const float* __restrict__ g, const float* __restrict__ bt,
    float* __restrict__ outf, ushort* __restrict__ outb) {
  const int row = blockIdx.x * 4 + (threadIdx.x >> 6);
  const int lane = threadIdx.x & 63;
  const size_t base = (size_t)row * ED;
  float4 x[3];
#pragma unroll
  for (int p = 0; p < 3; ++p) {
    const int idx = p * 256 + lane * 4;
    if (af) {
      x[p] = *(const float4*)&af[base + idx];
    } else {
      ushort4 u = *(const ushort4*)&ab[base + idx];
      x[p] = make_float4(bf2f(u.x), bf2f(u.y), bf2f(u.z), bf2f(u.w));
    }
    if (bsrc) {
      float4 bv = *(const float4*)&bsrc[base + idx];
      x[p].x += alpha * bv.x;
      x[p].y += alpha * bv.y;
      x[p].z += alpha * bv.z;
      x[p].w += alpha * bv.w;
    }
  }
  float s = 0.f;
#pragma unroll
  for (int p = 0; p < 3; ++p) s += x[p].x + x[p].y + x[p].z + x[p].w;
  for (int off = 32; off; off >>= 1) s += __shfl_xor(s, off);
  const float mean = s * (1.0f / 768.0f);
  float v = 0.f;
#pragma unroll
  for (int p = 0; p < 3; ++p) {
    float d0 = x[p].x - mean, d1 = x[p].y - mean;
    float d2 = x[p].z - mean, d3 = x[p].w - mean;
    v += d0 * d0 + d1 * d1 + d2 * d2 + d3 * d3;
  }
  for (int off = 32; off; off >>= 1) v += __shfl_xor(v, off);
  const float rs = rsqrtf(v * (1.0f / 768.0f) + LN_EPS);
#pragma unroll
  for (int p = 0; p < 3; ++p) {
    const int idx = p * 256 + lane * 4;
    const float4 gv = *(const float4*)&g[idx];
    const float4 bb = *(const float4*)&bt[idx];
    const float y0 = (x[p].x - mean) * rs * gv.x + bb.x;
    const float y1 = (x[p].y - mean) * rs * gv.y + bb.y;
    const float y2 = (x[p].z - mean) * rs * gv.z + bb.z;
    const float y3 = (x[p].w - mean) * rs * gv.w + bb.w;
    if (outf) *(float4*)&outf[base + idx] = make_float4(y0, y1, y2, y3);
    if (outb)
      *(ushort4*)&outb[base + idx] =
          make_ushort4(f2bf(y0), f2bf(y1), f2bf(y2), f2bf(y3));
  }
}

// ---------------------------------------------------------------------------
extern "C" void kernel_launch(void* const* d_in, const int* in_sizes, int n_in,
                              void* d_out, int out_size, void* d_ws,
                              size_t ws_size, hipStream_t stream) {
  (void)in_sizes; (void)n_in; (void)out_size; (void)ws_size;
  const float* emb     = (const float*)d_in[0];
  const float* context = (const float*)d_in[1];
  const float* sa_wq = (const float*)d_in[2];
  const float* sa_wk = (const float*)d_in[3];
  const float* sa_wv = (const float*)d_in[4];
  const float* sa_wo = (const float*)d_in[5];
  const float* sa_wo_b = (const float*)d_in[6];
  const float* sa_qn_g = (const float*)d_in[7];
  const float* sa_qn_b = (const float*)d_in[8];
  const float* sa_kn_g = (const float*)d_in[9];
  const float* sa_kn_b = (const float*)d_in[10];
  const float* ca_wq = (const float*)d_in[11];
  const float* ca_wk = (const float*)d_in[12];
  const float* ca_wv = (const float*)d_in[13];
  const float* ca_wo = (const float*)d_in[14];
  const float* ca_wo_b = (const float*)d_in[15];
  const float* ca_qn_g = (const float*)d_in[16];
  const float* ca_qn_b = (const float*)d_in[17];
  const float* ca_kn_g = (const float*)d_in[18];
  const float* ca_kn_b = (const float*)d_in[19];
  const float* mlp_w1 = (const float*)d_in[20];
  const float* mlp_b1 = (const float*)d_in[21];
  const float* mlp_w2 = (const float*)d_in[22];
  const float* mlp_b2 = (const float*)d_in[23];
  const float* ln1_g = (const float*)d_in[24];
  const float* ln1_b = (const float*)d_in[25];
  const float* ln2_g = (const float*)d_in[26];
  const float* ln2_b = (const float*)d_in[27];
  const float* ln3_g = (const float*)d_in[28];
  const float* ln3_b = (const float*)d_in[29];
  float* out = (float*)d_out;

  // ---- workspace layout (106.2 MB) ----
  const size_t R = TOT_R;  // 6291456
  ushort* U = (ushort*)d_ws;
  ushort* Qh  = U;             // bf16 head tensors (V region holds V^T)
  ushort* Kh  = U + R;
  ushort* Vh  = U + 2 * R;
  ushort* SH1 = U + 3 * R;     // emb_bf / AO_sa / X1_bf / AO_ca
  ushort* SH2 = U + 4 * R;     // ctx_bf / X2_bf
  ushort* WB  = U + 5 * R;     // transposed bf16 weights (9043968 elems)
  float*  X1  = (float*)(U + 5 * R + 9043968);  // fp32 residual (ln1 out)
  ushort* WOb = Qh;            // WO_sa / WO_ca bf16 out (Q dead post-flash)
  ushort* M2b = (ushort*)X1;   // MLP2 bf16 out (X1 dead after ln2 read)
  ushort* Hb  = Qh;            // MLP hidden [8192][3072] (spans Qh..SH1, dead)

  // WB sub-offsets (bf16 elems)
  ushort* w_saqkv = WB;                      // [2304][768] (q|k|v)
  ushort* w_sao   = WB + 1769472;            // [768][768]
  ushort* w_caq   = WB + 2359296;            // [768][768]
  ushort* w_cakv  = WB + 2949120;            // [1536][512] (k|v)
  ushort* w_cao   = WB + 3735552;            // [768][768]
  ushort* w_m1    = WB + 4325376;            // [3072][768]
  ushort* w_m2    = WB + 6684672;            // [768][3072]

  dim3 blk(256);

  // ---- one fused conversion launch ----
  CvtPack P;
  const float* srcs[12] = {sa_wq, sa_wk, sa_wv, sa_wo, ca_wq, ca_wk, ca_wv,
                           ca_wo, mlp_w1, mlp_w2, emb, context};
  ushort* dsts[12] = {w_saqkv, w_saqkv + 589824, w_saqkv + 1179648, w_sao,
                      w_caq, w_cakv, w_cakv + 393216, w_cao, w_m1, w_m2,
                      SH1, SH2};
  const int kds[12] = {ED, ED, ED, ED, ED, CD, CD, ED, ED, FD,
                       1572864, 262144};
  const int nds[12] = {ED, ED, ED, ED, ED, ED, ED, ED, FD, ED, 0, 0};
  int off = 0;
  for (int j = 0; j < 12; ++j) {
    P.src[j] = srcs[j]; P.dst[j] = dsts[j]; P.kd[j] = kds[j]; P.nd[j] = nds[j];
    P.off[j] = off;
    off += nds[j] ? (nds[j] >> 5) * (kds[j] >> 5) : (kds[j] + 255) >> 8;
  }
  P.off[12] = off;
  cvt_all<<<dim3(off), blk, 0, stream>>>(P);

  // ---- self-attention ----
  mfma_gemm<2><<<dim3(64, 18), blk, 0, stream>>>(
      SH1, w_saqkv, nullptr, Qh, 8192, 2304, ED, 10,
      sa_qn_g, sa_qn_b, sa_kn_g, sa_kn_b, 0, 1, 2);
  flash_mfma<<<dim3(96, 4), dim3(512), 0, stream>>>(Qh, Kh, Vh, SH1, SS);
  mfma_gemm<3><<<dim3(64, 6), blk, 0, stream>>>(
      SH1, w_sao, sa_wo_b, WOb, 8192, ED, ED, 0,
      nullptr, nullptr, nullptr, nullptr, -1, -1, -1);
  add_ln<<<dim3(2048), blk, 0, stream>>>(nullptr, WOb, emb, 2.0f,
                                         ln1_g, ln1_b, X1, SH1);

  // ---- cross-attention (Q and K/V projections fused in one dispatch) ----
  mfma_gemm_ca<<<dim3(576), blk, 0, stream>>>(
      SH1, w_caq, Qh, SH2, w_cakv, Kh,
      ca_qn_g, ca_qn_b, ca_kn_g, ca_kn_b);
  flash_mfma<<<dim3(96, 4), dim3(512), 0, stream>>>(Qh, Kh, Vh, SH1, TT);
  mfma_gemm<3><<<dim3(64, 6), blk, 0, stream>>>(
      SH1, w_cao, ca_wo_b, WOb, 8192, ED, ED, 0,
      nullptr, nullptr, nullptr, nullptr, -1, -1, -1);
  add_ln<<<dim3(2048), blk, 0, stream>>>(nullptr, WOb, X1, 1.0f,
                                         ln2_g, ln2_b, nullptr, SH2);

  // ---- MLP ----
  // MLP1: 256x256 8-wave deep-pipelined kernel (T3+T4 regime)
  mfma_gemm8<<<dim3(32, 12), dim3(512), 0, stream>>>(
      SH2, w_m1, mlp_b1, Hb, FD, ED);
  mfma_gemm<3><<<dim3(64, 6), blk, 0, stream>>>(
      Hb, w_m2, mlp_b2, M2b, 8192, ED, FD, 0,
      nullptr, nullptr, nullptr, nullptr, -1, -1, -1);
  add_ln<<<dim3(2048), blk, 0, stream>>>(nullptr, M2b, nullptr, 0.0f,
                                         ln3_g, ln3_b, out, nullptr);
}

// Round 17
// 327.622 us; speedup vs baseline: 1.0209x; 1.0209x over previous
//
#include <hip/hip_runtime.h>
#include <hip/hip_bf16.h>
#include <math.h>

#define NH 12
#define HD 64
#define ED 768
#define CD 512
#define FD 3072
#define BB 8
#define SS 1024
#define TT 256
#define LN_EPS 1e-5f
#define ATT_SCALE 0.125f
#define QSC_LOG2E 0.1803368801111204f  // ATT_SCALE * log2(e): softmax in base-2
#define P_M0 11.55f                    // fixed softmax max: |q||k|*scale*log2e < 11.545
#define TOT_R 6291456                  // B*NH*SS*HD elements per head-tensor region

typedef __attribute__((ext_vector_type(8))) __bf16 bf16x8;
typedef __attribute__((ext_vector_type(4))) __bf16 bf16x4;
typedef __attribute__((ext_vector_type(4))) float f32x4;

typedef const __attribute__((address_space(1))) void* gas1_t;
typedef __attribute__((address_space(3))) void* las3_t;

__device__ __forceinline__ void gl16(const void* g, void* l) {
  // async global->LDS, 16B per lane; LDS dest is wave-linear (base+lane*16)
  __builtin_amdgcn_global_load_lds((gas1_t)g, (las3_t)l, 16, 0, 0);
}

__device__ __forceinline__ ushort f2bf(float f) {
  union { __bf16 b; ushort u; } c;
  c.b = (__bf16)f;  // fptrunc RNE -> v_cvt_pk_bf16_f32 (compiler pairs them)
  return c.u;
}
__device__ __forceinline__ float bf2f(ushort u) {
  return __uint_as_float((unsigned)u << 16);
}

// fast GELU: x*sigmoid(1.5958(x+0.044715x^3)) via native exp2/rcp.
// |err| <= ~3e-4 absolute vs exact erf-GELU — far below bf16 output grid.
__device__ __forceinline__ float gelu_fast(float c) {
  const float x2 = c * c;
  const float ex = __builtin_amdgcn_exp2f(c * (-2.3022084f - 0.10294325f * x2));
  return c * __builtin_amdgcn_rcpf(1.0f + ex);
}

// Swizzled MFMA fragment read from a [rows][64]-ushort tile (128B rows).
// Element (row, 8*q8+e) lives at byte row*128 + ((q8^(row&7))<<4) + 2e.
__device__ __forceinline__ bf16x8 frag64(const ushort (*T)[64], int row, int q8) {
  return *(const bf16x8*)((const char*)T + row * 128 + ((q8 ^ (row & 7)) << 4));
}

// ---------------------------------------------------------------------------
// Fused conversion kernel: jobs 0..9 = W[K,N] fp32 -> WT[N,K] bf16 transposes,
// jobs 10..11 = flat fp32 -> bf16 converts. One launch for everything.
// ---------------------------------------------------------------------------
struct CvtPack {
  const float* src[12];
  ushort* dst[12];
  int kd[12];   // transpose: Kd ; flat: n4 element count
  int nd[12];   // transpose: Nd ; flat: 0
  int off[13];  // prefix block offsets
};

__global__ __launch_bounds__(256) void cvt_all(CvtPack P) {
  __shared__ float t[32][33];
  const int flat = blockIdx.x;
  int j = 0;
  while (j < 11 && flat >= P.off[j + 1]) ++j;
  const int rel = flat - P.off[j];
  if (P.nd[j] == 0) {  // flat convert
    const int i = rel * 256 + threadIdx.x;
    if (i < P.kd[j]) {
      float4 v = ((const float4*)P.src[j])[i];
      ((ushort4*)P.dst[j])[i] =
          make_ushort4(f2bf(v.x), f2bf(v.y), f2bf(v.z), f2bf(v.w));
    }
    return;
  }
  const int Kd = P.kd[j], Nd = P.nd[j];
  const int ntx = Nd >> 5;
  const int n0 = (rel % ntx) * 32, k0 = (rel / ntx) * 32;
  const float* W = P.src[j];
  ushort* WT = P.dst[j];
  const int tx = threadIdx.x & 31, ty = threadIdx.x >> 5;  // ty 0..7
#pragma unroll
  for (int r = 0; r < 4; ++r)
    t[ty + 8 * r][tx] = W[(size_t)(k0 + ty + 8 * r) * Nd + n0 + tx];
  __syncthreads();
#pragma unroll
  for (int r = 0; r < 4; ++r)
    WT[(size_t)(n0 + ty + 8 * r) * Kd + k0 + tx] = f2bf(t[tx][ty + 8 * r]);
}

// ---------------------------------------------------------------------------
// bf16 MFMA GEMM: C[M,N] = A[M,K] @ Wt[N,K]^T (+bias).
// Tile 128x128, BK=64, 256 thr = 4 waves in 2x2, each wave 64x64 = 4x4 frags
// of v_mfma_f32_16x16x32_bf16. Staging: global_load_lds width=16 into linear
// LDS with PRE-SWIZZLED global source (q8^=row&7); reads apply same XOR.
// PIPELINED (2-phase): double-buffered LDS, next K-tile's DMA issued BEFORE
// computing the current tile, ONE barrier per K-step.
// MODE 1: bf16 out + bias + fast GELU.  MODE 3: bf16 out + bias (no act).
// MODE 2: heads bf16 out, no bias; fused tensors along N (64-col head groups,
//         tensor stride TOT_R), token layout via sshift. Per-head LayerNorm
//         fused in-register for tensor t_q (folds QSC_LOG2E) and t_k.
//         Tensor t_v is written TRANSPOSED [B,H,D,Stok] (packed ushort4).
// ---------------------------------------------------------------------------
template <int MODE>
__global__ __launch_bounds__(256) void mfma_gemm(
    const ushort* __restrict__ A, const ushort* __restrict__ Wt,
    const float* __restrict__ bias, void* __restrict__ outp,
    int M, int N, int K, int sshift,
    const float* __restrict__ qg, const float* __restrict__ qb,
    const float* __restrict__ kg, const float* __restrict__ kb,
    int t_q, int t_k, int t_v) {
  __shared__ ushort As[2][128][64];  // 2 x 16 KB, 128B rows, swizzled quanta
  __shared__ ushort Bs[2][128][64];
  const int tid = threadIdx.x;
  const int m0 = blockIdx.x * 128, n0 = blockIdx.y * 128;
  const int lane = tid & 63;
  const int wr = ((tid >> 6) >> 1) * 64, wc = ((tid >> 6) & 1) * 64;
  const int l15 = lane & 15, g = lane >> 4;
  f32x4 acc[4][4] = {};

  auto stage = [&](int bi, int kt) {
#pragma unroll
    for (int p = 0; p < 4; ++p) {
      const int flat = p * 256 + tid;          // 16B-quantum index, wave-linear
      const int row = flat >> 3, q8 = flat & 7;
      const int kc = 8 * (q8 ^ (row & 7));     // inverse-swizzled source col
      gl16(&A[(size_t)(m0 + row) * K + kt + kc], (char*)As[bi] + flat * 16);
      gl16(&Wt[(size_t)(n0 + row) * K + kt + kc], (char*)Bs[bi] + flat * 16);
    }
  };

  stage(0, 0);
  __syncthreads();  // drains chunk-0 DMA (implicit vmcnt(0))
  int cur = 0;
  for (int kt = 0; kt < K; kt += 64) {
    if (kt + 64 < K) stage(cur ^ 1, kt + 64);  // in flight under compute
#pragma unroll
    for (int h = 0; h < 2; ++h) {
      bf16x8 af[4], bfv[4];
#pragma unroll
      for (int i = 0; i < 4; ++i) {
        af[i] = frag64(As[cur], wr + i * 16 + l15, 4 * h + g);
        bfv[i] = frag64(Bs[cur], wc + i * 16 + l15, 4 * h + g);
      }
#pragma unroll
      for (int i = 0; i < 4; ++i)
#pragma unroll
        for (int j = 0; j < 4; ++j)
          acc[i][j] = __builtin_amdgcn_mfma_f32_16x16x32_bf16(af[i], bfv[j],
                                                              acc[i][j], 0, 0, 0);
    }
    __syncthreads();  // next buffer complete; all reads of cur done
    cur ^= 1;
  }

  if (MODE == 2) {
    ushort* out = (ushort*)outp;
    const int Stok = 1 << sshift, smask = Stok - 1;
    const int ht0 = (n0 + wc) >> 6;            // wave-uniform head-column
    const int t = ht0 / NH, h = ht0 - t * NH;
    const bool isq = (t == t_q), isk = (t == t_k);
    if (isq || isk) {  // fused per-head LayerNorm over the wave's 64 cols
      const float* gg = isq ? qg : kg;
      const float* bb = isq ? qb : kb;
      const float osc = isq ? QSC_LOG2E : 1.0f;
      float gv[4], bv[4];
#pragma unroll
      for (int j = 0; j < 4; ++j) {
        gv[j] = gg[j * 16 + l15];
        bv[j] = bb[j * 16 + l15];
      }
#pragma unroll
      for (int i = 0; i < 4; ++i)
#pragma unroll
        for (int r = 0; r < 4; ++r) {
          float s = acc[i][0][r] + acc[i][1][r] + acc[i][2][r] + acc[i][3][r];
          float sq = acc[i][0][r] * acc[i][0][r] + acc[i][1][r] * acc[i][1][r] +
                     acc[i][2][r] * acc[i][2][r] + acc[i][3][r] * acc[i][3][r];
          s += __shfl_xor(s, 1);  sq += __shfl_xor(sq, 1);
          s += __shfl_xor(s, 2);  sq += __shfl_xor(sq, 2);
          s += __shfl_xor(s, 4);  sq += __shfl_xor(sq, 4);
          s += __shfl_xor(s, 8);  sq += __shfl_xor(sq, 8);
          const float mean = s * (1.0f / 64.0f);
          const float var = sq * (1.0f / 64.0f) - mean * mean;
          const float rs = rsqrtf(fmaxf(var, 0.0f) + LN_EPS);
#pragma unroll
          for (int j = 0; j < 4; ++j)
            acc[i][j][r] = ((acc[i][j][r] - mean) * rs * gv[j] + bv[j]) * osc;
        }
    }
    if (t == t_v) {  // transposed V^T output: [B,H,D=64,Stok], 4-s packs
#pragma unroll
      for (int i = 0; i < 4; ++i) {
        const int row = m0 + wr + i * 16 + g * 4;  // 4 consecutive tokens
        const int b = row >> sshift, s2 = row & smask;
        ushort* obase =
            out + (size_t)t * TOT_R + (((size_t)b * NH + h) * 64) * Stok + s2;
#pragma unroll
        for (int j = 0; j < 4; ++j) {
          const int d = j * 16 + l15;
          ushort4 pk = make_ushort4(f2bf(acc[i][j][0]), f2bf(acc[i][j][1]),
                                    f2bf(acc[i][j][2]), f2bf(acc[i][j][3]));
          *(ushort4*)&obase[(size_t)d * Stok] = pk;
        }
      }
    } else {
#pragma unroll
      for (int i = 0; i < 4; ++i)
#pragma unroll
        for (int r = 0; r < 4; ++r) {
          const int row = m0 + wr + i * 16 + g * 4 + r;
          const int b = row >> sshift, s2 = row & smask;
          ushort* orow =
              out + (size_t)t * TOT_R + (((size_t)b * NH + h) * Stok + s2) * 64;
#pragma unroll
          for (int j = 0; j < 4; ++j) orow[j * 16 + l15] = f2bf(acc[i][j][r]);
        }
    }
  } else {
#pragma unroll
    for (int i = 0; i < 4; ++i) {
#pragma unroll
      for (int j = 0; j < 4; ++j) {
        const int gc = n0 + wc + j * 16 + l15;
        const float bv = bias ? bias[gc] : 0.0f;
#pragma unroll
        for (int r = 0; r < 4; ++r) {
          const int row = m0 + wr + i * 16 + g * 4 + r;
          float c = acc[i][j][r] + bv;
          if (MODE == 1) c = gelu_fast(c);
          ((ushort*)outp)[(size_t)row * N + gc] = f2bf(c);
        }
      }
    }
  }
}

// ---------------------------------------------------------------------------
// Dual-job MODE-2 GEMM: fuses CA-Q and CA-KV projections into one dispatch.
// flat blocks [0,192): CAKV (M=2048, N=1536, K=512); [192,576): CAQ.
// ---------------------------------------------------------------------------
__global__ __launch_bounds__(256) void mfma_gemm_ca(
    const ushort* __restrict__ A0, const ushort* __restrict__ Wt0,
    void* __restrict__ out0,
    const ushort* __restrict__ A1, const ushort* __restrict__ Wt1,
    void* __restrict__ out1,
    const float* __restrict__ qg, const float* __restrict__ qb,
    const float* __restrict__ kg, const float* __restrict__ kb) {
  __shared__ ushort As[2][128][64];
  __shared__ ushort Bs[2][128][64];
  const int tid = threadIdx.x;
  const int fb = blockIdx.x;
  const ushort* A;
  const ushort* Wt;
  ushort* out;
  int m0, n0, K, sshift, t_q, t_k, t_v;
  if (fb < 192) {  // job B: CAKV
    A = A1; Wt = Wt1; out = (ushort*)out1;
    K = CD; sshift = 8;
    m0 = (fb & 15) * 128; n0 = (fb >> 4) * 128;
    t_q = -1; t_k = 0; t_v = 1;
  } else {         // job A: CAQ
    const int id = fb - 192;
    A = A0; Wt = Wt0; out = (ushort*)out0;
    K = ED; sshift = 10;
    m0 = (id & 63) * 128; n0 = (id >> 6) * 128;
    t_q = 0; t_k = -1; t_v = -1;
  }
  const int lane = tid & 63;
  const int wr = ((tid >> 6) >> 1) * 64, wc = ((tid >> 6) & 1) * 64;
  const int l15 = lane & 15, g = lane >> 4;
  f32x4 acc[4][4] = {};

  auto stage = [&](int bi, int kt) {
#pragma unroll
    for (int p = 0; p < 4; ++p) {
      const int flat = p * 256 + tid;
      const int row = flat >> 3, q8 = flat & 7;
      const int kc = 8 * (q8 ^ (row & 7));
      gl16(&A[(size_t)(m0 + row) * K + kt + kc], (char*)As[bi] + flat * 16);
      gl16(&Wt[(size_t)(n0 + row) * K + kt + kc], (char*)Bs[bi] + flat * 16);
    }
  };

  stage(0, 0);
  __syncthreads();
  int cur = 0;
  for (int kt = 0; kt < K; kt += 64) {
    if (kt + 64 < K) stage(cur ^ 1, kt + 64);
#pragma unroll
    for (int h = 0; h < 2; ++h) {
      bf16x8 af[4], bfv[4];
#pragma unroll
      for (int i = 0; i < 4; ++i) {
        af[i] = frag64(As[cur], wr + i * 16 + l15, 4 * h + g);
        bfv[i] = frag64(Bs[cur], wc + i * 16 + l15, 4 * h + g);
      }
#pragma unroll
      for (int i = 0; i < 4; ++i)
#pragma unroll
        for (int j = 0; j < 4; ++j)
          acc[i][j] = __builtin_amdgcn_mfma_f32_16x16x32_bf16(af[i], bfv[j],
                                                              acc[i][j], 0, 0, 0);
    }
    __syncthreads();
    cur ^= 1;
  }

  const int Stok = 1 << sshift, smask = Stok - 1;
  const int ht0 = (n0 + wc) >> 6;
  const int t = ht0 / NH, h = ht0 - t * NH;
  const bool isq = (t == t_q), isk = (t == t_k);
  if (isq || isk) {
    const float* gg = isq ? qg : kg;
    const float* bb = isq ? qb : kb;
    const float osc = isq ? QSC_LOG2E : 1.0f;
    float gv[4], bv[4];
#pragma unroll
    for (int j = 0; j < 4; ++j) {
      gv[j] = gg[j * 16 + l15];
      bv[j] = bb[j * 16 + l15];
    }
#pragma unroll
    for (int i = 0; i < 4; ++i)
#pragma unroll
      for (int r = 0; r < 4; ++r) {
        float s = acc[i][0][r] + acc[i][1][r] + acc[i][2][r] + acc[i][3][r];
        float sq = acc[i][0][r] * acc[i][0][r] + acc[i][1][r] * acc[i][1][r] +
                   acc[i][2][r] * acc[i][2][r] + acc[i][3][r] * acc[i][3][r];
        s += __shfl_xor(s, 1);  sq += __shfl_xor(sq, 1);
        s += __shfl_xor(s, 2);  sq += __shfl_xor(sq, 2);
        s += __shfl_xor(s, 4);  sq += __shfl_xor(sq, 4);
        s += __shfl_xor(s, 8);  sq += __shfl_xor(sq, 8);
        const float mean = s * (1.0f / 64.0f);
        const float var = sq * (1.0f / 64.0f) - mean * mean;
        const float rs = rsqrtf(fmaxf(var, 0.0f) + LN_EPS);
#pragma unroll
        for (int j = 0; j < 4; ++j)
          acc[i][j][r] = ((acc[i][j][r] - mean) * rs * gv[j] + bv[j]) * osc;
      }
  }
  if (t == t_v) {  // V^T output
#pragma unroll
    for (int i = 0; i < 4; ++i) {
      const int row = m0 + wr + i * 16 + g * 4;
      const int b = row >> sshift, s2 = row & smask;
      ushort* obase =
          out + (size_t)t * TOT_R + (((size_t)b * NH + h) * 64) * Stok + s2;
#pragma unroll
      for (int j = 0; j < 4; ++j) {
        const int d = j * 16 + l15;
        ushort4 pk = make_ushort4(f2bf(acc[i][j][0]), f2bf(acc[i][j][1]),
                                  f2bf(acc[i][j][2]), f2bf(acc[i][j][3]));
        *(ushort4*)&obase[(size_t)d * Stok] = pk;
      }
    }
  } else {
#pragma unroll
    for (int i = 0; i < 4; ++i)
#pragma unroll
      for (int r = 0; r < 4; ++r) {
        const int row = m0 + wr + i * 16 + g * 4 + r;
        const int b = row >> sshift, s2 = row & smask;
        ushort* orow =
            out + (size_t)t * TOT_R + (((size_t)b * NH + h) * Stok + s2) * 64;
#pragma unroll
        for (int j = 0; j < 4; ++j) orow[j * 16 + l15] = f2bf(acc[i][j][r]);
      }
  }
}

// ---------------------------------------------------------------------------
// MFMA flash attention v5 (unchanged since R8). Q bf16 [B*NH,1024,64]
// (LN epilogue folds ATT_SCALE*log2e), K bf16 [B*NH,Tkv,64], V^T bf16
// [B*NH,64,Tkv]. out bf16 [B,1024,768]. grid=(B*NH, 1024/256), block=512:
// 8 waves x 32 q-rows (2 subtiles). Key-permuted K staging, fixed-max base-2
// softmax, l via ones-rows, DMA-staged double buffers.
// ---------------------------------------------------------------------------
__global__ __launch_bounds__(512) void flash_mfma(
    const ushort* __restrict__ Q, const ushort* __restrict__ K,
    const ushort* __restrict__ V, ushort* __restrict__ out, int Tkv) {
  __shared__ ushort Ks[2][64][64];   // 16 KB  [perm key][d]
  __shared__ ushort Vt[2][80][64];   // 20 KB  [d][key]; rows 64..79 = ones
  __shared__ ushort Ps[8][16][64];   // 16 KB  per-wave P tile [qrow][key]
  const int bh = blockIdx.x;
  const int b = bh / NH, h = bh % NH;
  const int qt = blockIdx.y;
  const int tid = threadIdx.x;
  const int w = tid >> 6, lane = tid & 63;
  const int l15 = lane & 15, g = lane >> 4;
  const int srow = tid >> 3;                       // LDS staging row
  const int q8s = tid & 7;
  const int skc = 8 * (q8s ^ (srow & 7));          // pre-swizzled source col
  const int kperm = 4 * (srow & 15) + (srow >> 4); // key held by LDS K-row srow

  const ushort* Qb = Q + ((size_t)bh * SS + qt * 256) * 64;
  const ushort* Kb = K + (size_t)bh * Tkv * 64;
  const ushort* Vb = V + (size_t)bh * Tkv * 64;    // V^T: [64][Tkv]

  // ---- issue DMA for chunk 0 (K permuted, V^T identity) ----
  gl16(&Kb[(size_t)kperm * 64 + skc], (char*)Ks[0] + tid * 16);
  gl16(&Vb[(size_t)srow * Tkv + skc], (char*)Vt[0] + tid * 16);

  // ones rows of Vt (both buffers), written once, untouched by DMA
  if (tid < 256) {
    const int bi = tid >> 7, rq = tid & 127;
    const uint4 ov = make_uint4(0x3F803F80u, 0x3F803F80u, 0x3F803F80u, 0x3F803F80u);
    *(uint4*)((char*)Vt[bi] + (64 + (rq >> 3)) * 128 + ((rq & 7) << 4)) = ov;
  }

  // ---- Q fragments straight to registers (2 subtiles x 2 k-octs) ----
  const ushort* qr0 = Qb + (w * 32 + l15) * 64;
  const bf16x8 qf00 = *(const bf16x8*)&qr0[g * 8];
  const bf16x8 qf01 = *(const bf16x8*)&qr0[32 + g * 8];
  const bf16x8 qf10 = *(const bf16x8*)&qr0[16 * 64 + g * 8];
  const bf16x8 qf11 = *(const bf16x8*)&qr0[16 * 64 + 32 + g * 8];
  __syncthreads();  // drains chunk-0 DMA + ones writes

  f32x4 oa[2][5] = {};
  // P-write byte offset: row g*4+r, cols 4*l15..4*l15+3 (one b64), swizzled
  const int pwofs = ((((l15 >> 1) ^ ((g * 4) & 7)) << 4) | ((l15 & 1) << 3));

  const int nch = Tkv >> 6;
  int cur = 0;
  for (int ci = 0; ci < nch; ++ci) {
    if (ci + 1 < nch) {  // DMA next chunk into other buffer; lands by barrier
      const int cnx = (ci + 1) << 6;
      const int nxt = cur ^ 1;
      gl16(&Kb[(size_t)(cnx + kperm) * 64 + skc], (char*)Ks[nxt] + tid * 16);
      gl16(&Vb[(size_t)srow * Tkv + cnx + skc], (char*)Vt[nxt] + tid * 16);
    }

    // ---- QK^T: 32q x 64k per wave (16 MFMA, kf shared across subtiles) ----
    f32x4 s[2][4] = {};
    __builtin_amdgcn_s_setprio(1);
#pragma unroll
    for (int kb = 0; kb < 4; ++kb) {
      bf16x8 kf0 = frag64(Ks[cur], kb * 16 + l15, g);
      bf16x8 kf1 = frag64(Ks[cur], kb * 16 + l15, 4 + g);
      s[0][kb] = __builtin_amdgcn_mfma_f32_16x16x32_bf16(qf00, kf0, s[0][kb], 0, 0, 0);
      s[0][kb] = __builtin_amdgcn_mfma_f32_16x16x32_bf16(qf01, kf1, s[0][kb], 0, 0, 0);
      s[1][kb] = __builtin_amdgcn_mfma_f32_16x16x32_bf16(qf10, kf0, s[1][kb], 0, 0, 0);
      s[1][kb] = __builtin_amdgcn_mfma_f32_16x16x32_bf16(qf11, kf1, s[1][kb], 0, 0, 0);
    }
    __builtin_amdgcn_s_setprio(0);

    // ---- softmax (fixed max) + packed P write + frag read, per subtile ----
    bf16x8 pfr[2][2];
#pragma unroll
    for (int sub = 0; sub < 2; ++sub) {
#pragma unroll
      for (int r = 0; r < 4; ++r) {
        bf16x4 pk;
#pragma unroll
        for (int kbv = 0; kbv < 4; ++kbv)
          pk[kbv] = (__bf16)__builtin_amdgcn_exp2f(s[sub][kbv][r] - P_M0);
        *(bf16x4*)((char*)Ps[w] + (g * 4 + r) * 128 + (pwofs ^ ((r & 7) << 4))) = pk;
      }
      pfr[sub][0] = frag64(Ps[w], l15, g);
      pfr[sub][1] = frag64(Ps[w], l15, 4 + g);
    }

    // ---- PV: O[32q x 80d] += P @ [V | 1] (20 MFMA; oa[.][4] = row-sums) ----
    __builtin_amdgcn_s_setprio(1);
#pragma unroll
    for (int jd = 0; jd < 5; ++jd) {
      const int d = jd * 16 + l15;
      bf16x8 vf0 = frag64(Vt[cur], d, g);
      bf16x8 vf1 = frag64(Vt[cur], d, 4 + g);
      oa[0][jd] = __builtin_amdgcn_mfma_f32_16x16x32_bf16(pfr[0][0], vf0, oa[0][jd], 0, 0, 0);
      oa[0][jd] = __builtin_amdgcn_mfma_f32_16x16x32_bf16(pfr[0][1], vf1, oa[0][jd], 0, 0, 0);
      oa[1][jd] = __builtin_amdgcn_mfma_f32_16x16x32_bf16(pfr[1][0], vf0, oa[1][jd], 0, 0, 0);
      oa[1][jd] = __builtin_amdgcn_mfma_f32_16x16x32_bf16(pfr[1][1], vf1, oa[1][jd], 0, 0, 0);
    }
    __builtin_amdgcn_s_setprio(0);

    __syncthreads();  // all reads of cur done; next-chunk DMA drained
    cur ^= 1;
  }

#pragma unroll
  for (int sub = 0; sub < 2; ++sub)
#pragma unroll
    for (int r = 0; r < 4; ++r) {
      const int row = qt * 256 + w * 32 + sub * 16 + g * 4 + r;
      const float inv = 1.0f / oa[sub][4][r];
#pragma unroll
      for (int jd = 0; jd < 4; ++jd)
        out[((size_t)b * SS + row) * ED + h * 64 + jd * 16 + l15] =
            f2bf(oa[sub][jd][r] * inv);
    }
}

// ---------------------------------------------------------------------------
// y = LN(ab + alpha*rb) over E=768; ab, rb bf16 (rb optional).
// Write fp32 (outf) and/or bf16 (outb).
// Wave-per-row: block = 256 = 4 waves = 4 rows; no LDS, no barriers.
// ---------------------------------------------------------------------------
__global__ __launch_bounds__(256) void add_ln(
    const ushort* __restrict__ ab, const ushort* __restrict__ rb, float alpha,
    const float* __restrict__ g, const float* __restrict__ bt,
    float* __restrict__ outf, ushort* __restrict__ outb) {
  const int row = blockIdx.x * 4 + (threadIdx.x >> 6);
  const int lane = threadIdx.x & 63;
  const size_t base = (size_t)row * ED;
  float4 x[3];
#pragma unroll
  for (int p = 0; p < 3; ++p) {
    const int idx = p * 256 + lane * 4;
    ushort4 u = *(const ushort4*)&ab[base + idx];
    x[p] = make_float4(bf2f(u.x), bf2f(u.y), bf2f(u.z), bf2f(u.w));
    if (rb) {
      ushort4 rv = *(const ushort4*)&rb[base + idx];
      x[p].x += alpha * bf2f(rv.x);
      x[p].y += alpha * bf2f(rv.y);
      x[p].z += alpha * bf2f(rv.z);
      x[p].w += alpha * bf2f(rv.w);
    }
  }
  float s = 0.f;
#pragma unroll
  for (int p = 0; p < 3; ++p) s += x[p].x + x[p].y + x[p].z + x[p].w;
  for (int off = 32; off; off >>= 1) s += __shfl_xor(s, off);
  const float mean = s * (1.0f / 768.0f);
  float v = 0.f;
#pragma unroll
  for (int p = 0; p < 3; ++p) {
    float d0 = x[p].x - mean, d1 = x[p].y - mean;
    float d2 = x[p].z - mean, d3 = x[p].w - mean;
    v += d0 * d0 + d1 * d1 + d2 * d2 + d3 * d3;
  }
  for (int off = 32; off; off >>= 1) v += __shfl_xor(v, off);
  const float rs = rsqrtf(v * (1.0f / 768.0f) + LN_EPS);
#pragma unroll
  for (int p = 0; p < 3; ++p) {
    const int idx = p * 256 + lane * 4;
    const float4 gv = *(const float4*)&g[idx];
    const float4 bb = *(const float4*)&bt[idx];
    const float y0 = (x[p].x - mean) * rs * gv.x + bb.x;
    const float y1 = (x[p].y - mean) * rs * gv.y + bb.y;
    const float y2 = (x[p].z - mean) * rs * gv.z + bb.z;
    const float y3 = (x[p].w - mean) * rs * gv.w + bb.w;
    if (outf) *(float4*)&outf[base + idx] = make_float4(y0, y1, y2, y3);
    if (outb)
      *(ushort4*)&outb[base + idx] =
          make_ushort4(f2bf(y0), f2bf(y1), f2bf(y2), f2bf(y3));
  }
}

// ---------------------------------------------------------------------------
extern "C" void kernel_launch(void* const* d_in, const int* in_sizes, int n_in,
                              void* d_out, int out_size, void* d_ws,
                              size_t ws_size, hipStream_t stream) {
  (void)in_sizes; (void)n_in; (void)out_size; (void)ws_size;
  const float* emb     = (const float*)d_in[0];
  const float* context = (const float*)d_in[1];
  const float* sa_wq = (const float*)d_in[2];
  const float* sa_wk = (const float*)d_in[3];
  const float* sa_wv = (const float*)d_in[4];
  const float* sa_wo = (const float*)d_in[5];
  const float* sa_wo_b = (const float*)d_in[6];
  const float* sa_qn_g = (const float*)d_in[7];
  const float* sa_qn_b = (const float*)d_in[8];
  const float* sa_kn_g = (const float*)d_in[9];
  const float* sa_kn_b = (const float*)d_in[10];
  const float* ca_wq = (const float*)d_in[11];
  const float* ca_wk = (const float*)d_in[12];
  const float* ca_wv = (const float*)d_in[13];
  const float* ca_wo = (const float*)d_in[14];
  const float* ca_wo_b = (const float*)d_in[15];
  const float* ca_qn_g = (const float*)d_in[16];
  const float* ca_qn_b = (const float*)d_in[17];
  const float* ca_kn_g = (const float*)d_in[18];
  const float* ca_kn_b = (const float*)d_in[19];
  const float* mlp_w1 = (const float*)d_in[20];
  const float* mlp_b1 = (const float*)d_in[21];
  const float* mlp_w2 = (const float*)d_in[22];
  const float* mlp_b2 = (const float*)d_in[23];
  const float* ln1_g = (const float*)d_in[24];
  const float* ln1_b = (const float*)d_in[25];
  const float* ln2_g = (const float*)d_in[26];
  const float* ln2_b = (const float*)d_in[27];
  const float* ln3_g = (const float*)d_in[28];
  const float* ln3_b = (const float*)d_in[29];
  float* out = (float*)d_out;

  // ---- workspace layout (106.2 MB) ----
  const size_t R = TOT_R;  // 6291456
  ushort* U = (ushort*)d_ws;
  ushort* Qh  = U;             // bf16 head tensors (V region holds V^T)
  ushort* Kh  = U + R;
  ushort* Vh  = U + 2 * R;
  ushort* SH1 = U + 3 * R;     // X1_bf (ln1 out: CAQ input + ln2 residual)
  ushort* SH2 = U + 4 * R;     // ctx_bf, then X2_bf, then M2b
  ushort* EB  = U + 5 * R;     // emb_bf (preserved: QKV input + ln1 residual)
  ushort* AO  = U + 6 * R;     // flash attention output (SA, then CA)
  ushort* WB  = U + 7 * R;     // transposed bf16 weights (9043968 elems)
  ushort* WOb = Qh;            // WO_sa / WO_ca bf16 out (Q dead post-flash)
  ushort* Hb  = Qh;            // MLP hidden [8192][3072] (spans Qh..SH1, dead)
  ushort* M2b = SH2;           // MLP2 bf16 out (SH2 dead after MLP1 reads it)

  // WB sub-offsets (bf16 elems)
  ushort* w_saqkv = WB;                      // [2304][768] (q|k|v)
  ushort* w_sao   = WB + 1769472;            // [768][768]
  ushort* w_caq   = WB + 2359296;            // [768][768]
  ushort* w_cakv  = WB + 2949120;            // [1536][512] (k|v)
  ushort* w_cao   = WB + 3735552;            // [768][768]
  ushort* w_m1    = WB + 4325376;            // [3072][768]
  ushort* w_m2    = WB + 6684672;            // [768][3072]

  dim3 blk(256);

  // ---- one fused conversion launch ----
  CvtPack P;
  const float* srcs[12] = {sa_wq, sa_wk, sa_wv, sa_wo, ca_wq, ca_wk, ca_wv,
                           ca_wo, mlp_w1, mlp_w2, emb, context};
  ushort* dsts[12] = {w_saqkv, w_saqkv + 589824, w_saqkv + 1179648, w_sao,
                      w_caq, w_cakv, w_cakv + 393216, w_cao, w_m1, w_m2,
                      EB, SH2};
  const int kds[12] = {ED, ED, ED, ED, ED, CD, CD, ED, ED, FD,
                       1572864, 262144};
  const int nds[12] = {ED, ED, ED, ED, ED, ED, ED, ED, FD, ED, 0, 0};
  int off = 0;
  for (int j = 0; j < 12; ++j) {
    P.src[j] = srcs[j]; P.dst[j] = dsts[j]; P.kd[j] = kds[j]; P.nd[j] = nds[j];
    P.off[j] = off;
    off += nds[j] ? (nds[j] >> 5) * (kds[j] >> 5) : (kds[j] + 255) >> 8;
  }
  P.off[12] = off;
  cvt_all<<<dim3(off), blk, 0, stream>>>(P);

  // ---- self-attention ----
  mfma_gemm<2><<<dim3(64, 18), blk, 0, stream>>>(
      EB, w_saqkv, nullptr, Qh, 8192, 2304, ED, 10,
      sa_qn_g, sa_qn_b, sa_kn_g, sa_kn_b, 0, 1, 2);
  flash_mfma<<<dim3(96, 4), dim3(512), 0, stream>>>(Qh, Kh, Vh, AO, SS);
  mfma_gemm<3><<<dim3(64, 6), blk, 0, stream>>>(
      AO, w_sao, sa_wo_b, WOb, 8192, ED, ED, 0,
      nullptr, nullptr, nullptr, nullptr, -1, -1, -1);
  add_ln<<<dim3(2048), blk, 0, stream>>>(WOb, EB, 2.0f, ln1_g, ln1_b,
                                         nullptr, SH1);

  // ---- cross-attention (Q and K/V projections fused in one dispatch) ----
  mfma_gemm_ca<<<dim3(576), blk, 0, stream>>>(
      SH1, w_caq, Qh, SH2, w_cakv, Kh,
      ca_qn_g, ca_qn_b, ca_kn_g, ca_kn_b);
  flash_mfma<<<dim3(96, 4), dim3(512), 0, stream>>>(Qh, Kh, Vh, AO, TT);
  mfma_gemm<3><<<dim3(64, 6), blk, 0, stream>>>(
      AO, w_cao, ca_wo_b, WOb, 8192, ED, ED, 0,
      nullptr, nullptr, nullptr, nullptr, -1, -1, -1);
  add_ln<<<dim3(2048), blk, 0, stream>>>(WOb, SH1, 1.0f, ln2_g, ln2_b,
                                         nullptr, SH2);

  // ---- MLP ----
  mfma_gemm<1><<<dim3(64, 24), blk, 0, stream>>>(
      SH2, w_m1, mlp_b1, Hb, 8192, FD, ED, 0,
      nullptr, nullptr, nullptr, nullptr, -1, -1, -1);
  mfma_gemm<3><<<dim3(64, 6), blk, 0, stream>>>(
      Hb, w_m2, mlp_b2, M2b, 8192, ED, FD, 0,
      nullptr, nullptr, nullptr, nullptr, -1, -1, -1);
  add_ln<<<dim3(2048), blk, 0, stream>>>(M2b, nullptr, 0.0f, ln3_g, ln3_b,
                                         out, nullptr);
}

// Round 18
// 325.805 us; speedup vs baseline: 1.0266x; 1.0056x over previous
//
#include <hip/hip_runtime.h>
#include <hip/hip_bf16.h>
#include <math.h>

#define NH 12
#define HD 64
#define ED 768
#define CD 512
#define FD 3072
#define BB 8
#define SS 1024
#define TT 256
#define LN_EPS 1e-5f
#define ATT_SCALE 0.125f
#define QSC_LOG2E 0.1803368801111204f  // ATT_SCALE * log2(e): softmax in base-2
#define P_M0 11.55f                    // fixed softmax max: |q||k|*scale*log2e < 11.545
#define TOT_R 6291456                  // B*NH*SS*HD elements per head-tensor region

typedef __attribute__((ext_vector_type(8))) __bf16 bf16x8;
typedef __attribute__((ext_vector_type(4))) __bf16 bf16x4;
typedef __attribute__((ext_vector_type(4))) float f32x4;

typedef const __attribute__((address_space(1))) void* gas1_t;
typedef __attribute__((address_space(3))) void* las3_t;

__device__ __forceinline__ void gl16(const void* g, void* l) {
  // async global->LDS, 16B per lane; LDS dest is wave-linear (base+lane*16)
  __builtin_amdgcn_global_load_lds((gas1_t)g, (las3_t)l, 16, 0, 0);
}

__device__ __forceinline__ ushort f2bf(float f) {
  union { __bf16 b; ushort u; } c;
  c.b = (__bf16)f;  // fptrunc RNE -> v_cvt_pk_bf16_f32 (compiler pairs them)
  return c.u;
}
__device__ __forceinline__ float bf2f(ushort u) {
  return __uint_as_float((unsigned)u << 16);
}

// fast GELU: x*sigmoid(1.5958(x+0.044715x^3)) via native exp2/rcp.
// |err| <= ~3e-4 absolute vs exact erf-GELU — far below bf16 output grid.
__device__ __forceinline__ float gelu_fast(float c) {
  const float x2 = c * c;
  const float ex = __builtin_amdgcn_exp2f(c * (-2.3022084f - 0.10294325f * x2));
  return c * __builtin_amdgcn_rcpf(1.0f + ex);
}

// Swizzled MFMA fragment read from a [rows][64]-ushort tile (128B rows).
// Element (row, 8*q8+e) lives at byte row*128 + ((q8^(row&7))<<4) + 2e.
__device__ __forceinline__ bf16x8 frag64(const ushort (*T)[64], int row, int q8) {
  return *(const bf16x8*)((const char*)T + row * 128 + ((q8 ^ (row & 7)) << 4));
}

// ---------------------------------------------------------------------------
// Fused conversion kernel: jobs 0..9 = W[K,N] fp32 -> WT[N,K] bf16 transposes,
// jobs 10..11 = flat fp32 -> bf16 converts. One launch for everything.
// Transpose output vectorized: ushort4 (8B/lane) stores; LDS reads ~2-way.
// ---------------------------------------------------------------------------
struct CvtPack {
  const float* src[12];
  ushort* dst[12];
  int kd[12];   // transpose: Kd ; flat: n4 element count
  int nd[12];   // transpose: Nd ; flat: 0
  int off[13];  // prefix block offsets
};

__global__ __launch_bounds__(256) void cvt_all(CvtPack P) {
  __shared__ float t[32][33];
  const int flat = blockIdx.x;
  int j = 0;
  while (j < 11 && flat >= P.off[j + 1]) ++j;
  const int rel = flat - P.off[j];
  if (P.nd[j] == 0) {  // flat convert
    const int i = rel * 256 + threadIdx.x;
    if (i < P.kd[j]) {
      float4 v = ((const float4*)P.src[j])[i];
      ((ushort4*)P.dst[j])[i] =
          make_ushort4(f2bf(v.x), f2bf(v.y), f2bf(v.z), f2bf(v.w));
    }
    return;
  }
  const int Kd = P.kd[j], Nd = P.nd[j];
  const int ntx = Nd >> 5;
  const int n0 = (rel % ntx) * 32, k0 = (rel / ntx) * 32;
  const float* W = P.src[j];
  ushort* WT = P.dst[j];
  const int tx = threadIdx.x & 31, ty = threadIdx.x >> 5;  // ty 0..7
#pragma unroll
  for (int r = 0; r < 4; ++r)
    t[ty + 8 * r][tx] = W[(size_t)(k0 + ty + 8 * r) * Nd + n0 + tx];
  __syncthreads();
  {  // out: 32 n-rows x 8 k-quads; one ushort4 (8B) store per thread
    const int n = threadIdx.x >> 3, q = threadIdx.x & 7;
    ushort4 pk = make_ushort4(f2bf(t[q * 4 + 0][n]), f2bf(t[q * 4 + 1][n]),
                              f2bf(t[q * 4 + 2][n]), f2bf(t[q * 4 + 3][n]));
    *(ushort4*)&WT[(size_t)(n0 + n) * Kd + k0 + q * 4] = pk;
  }
}

// ---------------------------------------------------------------------------
// bf16 MFMA GEMM: C[M,N] = A[M,K] @ Wt[N,K]^T (+bias).
// Tile 128x128, BK=64, 256 thr = 4 waves in 2x2, each wave 64x64 = 4x4 frags
// of v_mfma_f32_16x16x32_bf16. Staging: global_load_lds width=16 into linear
// LDS with PRE-SWIZZLED global source (q8^=row&7); reads apply same XOR.
// PIPELINED (2-phase): double-buffered LDS, next K-tile's DMA issued BEFORE
// computing the current tile, ONE barrier per K-step.
// MODE 1: bf16 out + bias + fast GELU.  MODE 3: bf16 out + bias (no act).
// MODE 2: heads bf16 out, no bias; fused tensors along N (64-col head groups,
//         tensor stride TOT_R), token layout via sshift. Per-head LayerNorm
//         fused in-register for tensor t_q (folds QSC_LOG2E) and t_k.
//         Tensor t_v is written TRANSPOSED [B,H,D,Stok] (packed ushort4).
// ---------------------------------------------------------------------------
template <int MODE>
__global__ __launch_bounds__(256) void mfma_gemm(
    const ushort* __restrict__ A, const ushort* __restrict__ Wt,
    const float* __restrict__ bias, void* __restrict__ outp,
    int M, int N, int K, int sshift,
    const float* __restrict__ qg, const float* __restrict__ qb,
    const float* __restrict__ kg, const float* __restrict__ kb,
    int t_q, int t_k, int t_v) {
  __shared__ ushort As[2][128][64];  // 2 x 16 KB, 128B rows, swizzled quanta
  __shared__ ushort Bs[2][128][64];
  const int tid = threadIdx.x;
  const int m0 = blockIdx.x * 128, n0 = blockIdx.y * 128;
  const int lane = tid & 63;
  const int wr = ((tid >> 6) >> 1) * 64, wc = ((tid >> 6) & 1) * 64;
  const int l15 = lane & 15, g = lane >> 4;
  f32x4 acc[4][4] = {};

  auto stage = [&](int bi, int kt) {
#pragma unroll
    for (int p = 0; p < 4; ++p) {
      const int flat = p * 256 + tid;          // 16B-quantum index, wave-linear
      const int row = flat >> 3, q8 = flat & 7;
      const int kc = 8 * (q8 ^ (row & 7));     // inverse-swizzled source col
      gl16(&A[(size_t)(m0 + row) * K + kt + kc], (char*)As[bi] + flat * 16);
      gl16(&Wt[(size_t)(n0 + row) * K + kt + kc], (char*)Bs[bi] + flat * 16);
    }
  };

  stage(0, 0);
  __syncthreads();  // drains chunk-0 DMA (implicit vmcnt(0))
  int cur = 0;
  for (int kt = 0; kt < K; kt += 64) {
    if (kt + 64 < K) stage(cur ^ 1, kt + 64);  // in flight under compute
#pragma unroll
    for (int h = 0; h < 2; ++h) {
      bf16x8 af[4], bfv[4];
#pragma unroll
      for (int i = 0; i < 4; ++i) {
        af[i] = frag64(As[cur], wr + i * 16 + l15, 4 * h + g);
        bfv[i] = frag64(Bs[cur], wc + i * 16 + l15, 4 * h + g);
      }
#pragma unroll
      for (int i = 0; i < 4; ++i)
#pragma unroll
        for (int j = 0; j < 4; ++j)
          acc[i][j] = __builtin_amdgcn_mfma_f32_16x16x32_bf16(af[i], bfv[j],
                                                              acc[i][j], 0, 0, 0);
    }
    __syncthreads();  // next buffer complete; all reads of cur done
    cur ^= 1;
  }

  if (MODE == 2) {
    ushort* out = (ushort*)outp;
    const int Stok = 1 << sshift, smask = Stok - 1;
    const int ht0 = (n0 + wc) >> 6;            // wave-uniform head-column
    const int t = ht0 / NH, h = ht0 - t * NH;
    const bool isq = (t == t_q), isk = (t == t_k);
    if (isq || isk) {  // fused per-head LayerNorm over the wave's 64 cols
      const float* gg = isq ? qg : kg;
      const float* bb = isq ? qb : kb;
      const float osc = isq ? QSC_LOG2E : 1.0f;
      float gv[4], bv[4];
#pragma unroll
      for (int j = 0; j < 4; ++j) {
        gv[j] = gg[j * 16 + l15];
        bv[j] = bb[j * 16 + l15];
      }
#pragma unroll
      for (int i = 0; i < 4; ++i)
#pragma unroll
        for (int r = 0; r < 4; ++r) {
          float s = acc[i][0][r] + acc[i][1][r] + acc[i][2][r] + acc[i][3][r];
          float sq = acc[i][0][r] * acc[i][0][r] + acc[i][1][r] * acc[i][1][r] +
                     acc[i][2][r] * acc[i][2][r] + acc[i][3][r] * acc[i][3][r];
          s += __shfl_xor(s, 1);  sq += __shfl_xor(sq, 1);
          s += __shfl_xor(s, 2);  sq += __shfl_xor(sq, 2);
          s += __shfl_xor(s, 4);  sq += __shfl_xor(sq, 4);
          s += __shfl_xor(s, 8);  sq += __shfl_xor(sq, 8);
          const float mean = s * (1.0f / 64.0f);
          const float var = sq * (1.0f / 64.0f) - mean * mean;
          const float rs = rsqrtf(fmaxf(var, 0.0f) + LN_EPS);
#pragma unroll
          for (int j = 0; j < 4; ++j)
            acc[i][j][r] = ((acc[i][j][r] - mean) * rs * gv[j] + bv[j]) * osc;
        }
    }
    if (t == t_v) {  // transposed V^T output: [B,H,D=64,Stok], 4-s packs
#pragma unroll
      for (int i = 0; i < 4; ++i) {
        const int row = m0 + wr + i * 16 + g * 4;  // 4 consecutive tokens
        const int b = row >> sshift, s2 = row & smask;
        ushort* obase =
            out + (size_t)t * TOT_R + (((size_t)b * NH + h) * 64) * Stok + s2;
#pragma unroll
        for (int j = 0; j < 4; ++j) {
          const int d = j * 16 + l15;
          ushort4 pk = make_ushort4(f2bf(acc[i][j][0]), f2bf(acc[i][j][1]),
                                    f2bf(acc[i][j][2]), f2bf(acc[i][j][3]));
          *(ushort4*)&obase[(size_t)d * Stok] = pk;
        }
      }
    } else {
#pragma unroll
      for (int i = 0; i < 4; ++i)
#pragma unroll
        for (int r = 0; r < 4; ++r) {
          const int row = m0 + wr + i * 16 + g * 4 + r;
          const int b = row >> sshift, s2 = row & smask;
          ushort* orow =
              out + (size_t)t * TOT_R + (((size_t)b * NH + h) * Stok + s2) * 64;
#pragma unroll
          for (int j = 0; j < 4; ++j) orow[j * 16 + l15] = f2bf(acc[i][j][r]);
        }
    }
  } else {
#pragma unroll
    for (int i = 0; i < 4; ++i) {
#pragma unroll
      for (int j = 0; j < 4; ++j) {
        const int gc = n0 + wc + j * 16 + l15;
        const float bv = bias ? bias[gc] : 0.0f;
#pragma unroll
        for (int r = 0; r < 4; ++r) {
          const int row = m0 + wr + i * 16 + g * 4 + r;
          float c = acc[i][j][r] + bv;
          if (MODE == 1) c = gelu_fast(c);
          ((ushort*)outp)[(size_t)row * N + gc] = f2bf(c);
        }
      }
    }
  }
}

// ---------------------------------------------------------------------------
// Dual-job MODE-2 GEMM: fuses CA-Q and CA-KV projections into one dispatch.
// flat blocks [0,192): CAKV (M=2048, N=1536, K=512); [192,576): CAQ.
// ---------------------------------------------------------------------------
__global__ __launch_bounds__(256) void mfma_gemm_ca(
    const ushort* __restrict__ A0, const ushort* __restrict__ Wt0,
    void* __restrict__ out0,
    const ushort* __restrict__ A1, const ushort* __restrict__ Wt1,
    void* __restrict__ out1,
    const float* __restrict__ qg, const float* __restrict__ qb,
    const float* __restrict__ kg, const float* __restrict__ kb) {
  __shared__ ushort As[2][128][64];
  __shared__ ushort Bs[2][128][64];
  const int tid = threadIdx.x;
  const int fb = blockIdx.x;
  const ushort* A;
  const ushort* Wt;
  ushort* out;
  int m0, n0, K, sshift, t_q, t_k, t_v;
  if (fb < 192) {  // job B: CAKV
    A = A1; Wt = Wt1; out = (ushort*)out1;
    K = CD; sshift = 8;
    m0 = (fb & 15) * 128; n0 = (fb >> 4) * 128;
    t_q = -1; t_k = 0; t_v = 1;
  } else {         // job A: CAQ
    const int id = fb - 192;
    A = A0; Wt = Wt0; out = (ushort*)out0;
    K = ED; sshift = 10;
    m0 = (id & 63) * 128; n0 = (id >> 6) * 128;
    t_q = 0; t_k = -1; t_v = -1;
  }
  const int lane = tid & 63;
  const int wr = ((tid >> 6) >> 1) * 64, wc = ((tid >> 6) & 1) * 64;
  const int l15 = lane & 15, g = lane >> 4;
  f32x4 acc[4][4] = {};

  auto stage = [&](int bi, int kt) {
#pragma unroll
    for (int p = 0; p < 4; ++p) {
      const int flat = p * 256 + tid;
      const int row = flat >> 3, q8 = flat & 7;
      const int kc = 8 * (q8 ^ (row & 7));
      gl16(&A[(size_t)(m0 + row) * K + kt + kc], (char*)As[bi] + flat * 16);
      gl16(&Wt[(size_t)(n0 + row) * K + kt + kc], (char*)Bs[bi] + flat * 16);
    }
  };

  stage(0, 0);
  __syncthreads();
  int cur = 0;
  for (int kt = 0; kt < K; kt += 64) {
    if (kt + 64 < K) stage(cur ^ 1, kt + 64);
#pragma unroll
    for (int h = 0; h < 2; ++h) {
      bf16x8 af[4], bfv[4];
#pragma unroll
      for (int i = 0; i < 4; ++i) {
        af[i] = frag64(As[cur], wr + i * 16 + l15, 4 * h + g);
        bfv[i] = frag64(Bs[cur], wc + i * 16 + l15, 4 * h + g);
      }
#pragma unroll
      for (int i = 0; i < 4; ++i)
#pragma unroll
        for (int j = 0; j < 4; ++j)
          acc[i][j] = __builtin_amdgcn_mfma_f32_16x16x32_bf16(af[i], bfv[j],
                                                              acc[i][j], 0, 0, 0);
    }
    __syncthreads();
    cur ^= 1;
  }

  const int Stok = 1 << sshift, smask = Stok - 1;
  const int ht0 = (n0 + wc) >> 6;
  const int t = ht0 / NH, h = ht0 - t * NH;
  const bool isq = (t == t_q), isk = (t == t_k);
  if (isq || isk) {
    const float* gg = isq ? qg : kg;
    const float* bb = isq ? qb : kb;
    const float osc = isq ? QSC_LOG2E : 1.0f;
    float gv[4], bv[4];
#pragma unroll
    for (int j = 0; j < 4; ++j) {
      gv[j] = gg[j * 16 + l15];
      bv[j] = bb[j * 16 + l15];
    }
#pragma unroll
    for (int i = 0; i < 4; ++i)
#pragma unroll
      for (int r = 0; r < 4; ++r) {
        float s = acc[i][0][r] + acc[i][1][r] + acc[i][2][r] + acc[i][3][r];
        float sq = acc[i][0][r] * acc[i][0][r] + acc[i][1][r] * acc[i][1][r] +
                   acc[i][2][r] * acc[i][2][r] + acc[i][3][r] * acc[i][3][r];
        s += __shfl_xor(s, 1);  sq += __shfl_xor(sq, 1);
        s += __shfl_xor(s, 2);  sq += __shfl_xor(sq, 2);
        s += __shfl_xor(s, 4);  sq += __shfl_xor(sq, 4);
        s += __shfl_xor(s, 8);  sq += __shfl_xor(sq, 8);
        const float mean = s * (1.0f / 64.0f);
        const float var = sq * (1.0f / 64.0f) - mean * mean;
        const float rs = rsqrtf(fmaxf(var, 0.0f) + LN_EPS);
#pragma unroll
        for (int j = 0; j < 4; ++j)
          acc[i][j][r] = ((acc[i][j][r] - mean) * rs * gv[j] + bv[j]) * osc;
      }
  }
  if (t == t_v) {  // V^T output
#pragma unroll
    for (int i = 0; i < 4; ++i) {
      const int row = m0 + wr + i * 16 + g * 4;
      const int b = row >> sshift, s2 = row & smask;
      ushort* obase =
          out + (size_t)t * TOT_R + (((size_t)b * NH + h) * 64) * Stok + s2;
#pragma unroll
      for (int j = 0; j < 4; ++j) {
        const int d = j * 16 + l15;
        ushort4 pk = make_ushort4(f2bf(acc[i][j][0]), f2bf(acc[i][j][1]),
                                  f2bf(acc[i][j][2]), f2bf(acc[i][j][3]));
        *(ushort4*)&obase[(size_t)d * Stok] = pk;
      }
    }
  } else {
#pragma unroll
    for (int i = 0; i < 4; ++i)
#pragma unroll
      for (int r = 0; r < 4; ++r) {
        const int row = m0 + wr + i * 16 + g * 4 + r;
        const int b = row >> sshift, s2 = row & smask;
        ushort* orow =
            out + (size_t)t * TOT_R + (((size_t)b * NH + h) * Stok + s2) * 64;
#pragma unroll
        for (int j = 0; j < 4; ++j) orow[j * 16 + l15] = f2bf(acc[i][j][r]);
      }
  }
}

// ---------------------------------------------------------------------------
// MFMA flash attention v6. Q bf16 [B*NH,1024,64] (LN epilogue folds
// ATT_SCALE*log2e), K bf16 [B*NH,Tkv,64], V^T bf16 [B*NH,64,Tkv].
// out bf16 [B,1024,768]. grid = (B*NH, 1024/128), block = 512: 8 waves x
// 16 q-rows — 768 blocks = 3.0 blocks/CU EVEN (v5's 384 blocks at 3-resident
// left half the CUs running 2 sequential blocks: ~33% tail). Key-permuted K
// staging, fixed-max base-2 softmax, l via ones-rows, DMA-staged dbuf.
// ---------------------------------------------------------------------------
__global__ __launch_bounds__(512) void flash_mfma(
    const ushort* __restrict__ Q, const ushort* __restrict__ K,
    const ushort* __restrict__ V, ushort* __restrict__ out, int Tkv) {
  __shared__ ushort Ks[2][64][64];   // 16 KB  [perm key][d]
  __shared__ ushort Vt[2][80][64];   // 20 KB  [d][key]; rows 64..79 = ones
  __shared__ ushort Ps[8][16][64];   // 16 KB  per-wave P tile [qrow][key]
  const int bh = blockIdx.x;
  const int b = bh / NH, h = bh % NH;
  const int qt = blockIdx.y;
  const int tid = threadIdx.x;
  const int w = tid >> 6, lane = tid & 63;
  const int l15 = lane & 15, g = lane >> 4;
  const int srow = tid >> 3;                       // LDS staging row
  const int q8s = tid & 7;
  const int skc = 8 * (q8s ^ (srow & 7));          // pre-swizzled source col
  const int kperm = 4 * (srow & 15) + (srow >> 4); // key held by LDS K-row srow

  const ushort* Qb = Q + ((size_t)bh * SS + qt * 128) * 64;
  const ushort* Kb = K + (size_t)bh * Tkv * 64;
  const ushort* Vb = V + (size_t)bh * Tkv * 64;    // V^T: [64][Tkv]

  // ---- issue DMA for chunk 0 (K permuted, V^T identity) ----
  gl16(&Kb[(size_t)kperm * 64 + skc], (char*)Ks[0] + tid * 16);
  gl16(&Vb[(size_t)srow * Tkv + skc], (char*)Vt[0] + tid * 16);

  // ones rows of Vt (both buffers), written once, untouched by DMA
  if (tid < 256) {
    const int bi = tid >> 7, rq = tid & 127;
    const uint4 ov = make_uint4(0x3F803F80u, 0x3F803F80u, 0x3F803F80u, 0x3F803F80u);
    *(uint4*)((char*)Vt[bi] + (64 + (rq >> 3)) * 128 + ((rq & 7) << 4)) = ov;
  }

  // ---- Q fragments straight to registers (16 q-rows/wave, 2 k-octs) ----
  const ushort* qr0 = Qb + (w * 16 + l15) * 64;
  const bf16x8 qf0 = *(const bf16x8*)&qr0[g * 8];
  const bf16x8 qf1 = *(const bf16x8*)&qr0[32 + g * 8];
  __syncthreads();  // drains chunk-0 DMA + ones writes

  f32x4 oa[5] = {};
  // P-write byte offset: row g*4+r, cols 4*l15..4*l15+3 (one b64), swizzled
  const int pwofs = ((((l15 >> 1) ^ ((g * 4) & 7)) << 4) | ((l15 & 1) << 3));

  const int nch = Tkv >> 6;
  int cur = 0;
  for (int ci = 0; ci < nch; ++ci) {
    if (ci + 1 < nch) {  // DMA next chunk into other buffer; lands by barrier
      const int cnx = (ci + 1) << 6;
      const int nxt = cur ^ 1;
      gl16(&Kb[(size_t)(cnx + kperm) * 64 + skc], (char*)Ks[nxt] + tid * 16);
      gl16(&Vb[(size_t)srow * Tkv + cnx + skc], (char*)Vt[nxt] + tid * 16);
    }

    // ---- QK^T: 16q x 64k per wave (8 MFMA) ----
    f32x4 s[4] = {};
    __builtin_amdgcn_s_setprio(1);
#pragma unroll
    for (int kb = 0; kb < 4; ++kb) {
      bf16x8 kf0 = frag64(Ks[cur], kb * 16 + l15, g);
      bf16x8 kf1 = frag64(Ks[cur], kb * 16 + l15, 4 + g);
      s[kb] = __builtin_amdgcn_mfma_f32_16x16x32_bf16(qf0, kf0, s[kb], 0, 0, 0);
      s[kb] = __builtin_amdgcn_mfma_f32_16x16x32_bf16(qf1, kf1, s[kb], 0, 0, 0);
    }
    __builtin_amdgcn_s_setprio(0);

    // ---- softmax (fixed max) + packed P write + frag read ----
#pragma unroll
    for (int r = 0; r < 4; ++r) {
      bf16x4 pk;
#pragma unroll
      for (int kbv = 0; kbv < 4; ++kbv)
        pk[kbv] = (__bf16)__builtin_amdgcn_exp2f(s[kbv][r] - P_M0);
      *(bf16x4*)((char*)Ps[w] + (g * 4 + r) * 128 + (pwofs ^ ((r & 7) << 4))) = pk;
    }
    const bf16x8 pf0 = frag64(Ps[w], l15, g);
    const bf16x8 pf1 = frag64(Ps[w], l15, 4 + g);

    // ---- PV: O[16q x 80d] += P @ [V | 1] (10 MFMA; oa[4] = row-sums) ----
    __builtin_amdgcn_s_setprio(1);
#pragma unroll
    for (int jd = 0; jd < 5; ++jd) {
      const int d = jd * 16 + l15;
      bf16x8 vf0 = frag64(Vt[cur], d, g);
      bf16x8 vf1 = frag64(Vt[cur], d, 4 + g);
      oa[jd] = __builtin_amdgcn_mfma_f32_16x16x32_bf16(pf0, vf0, oa[jd], 0, 0, 0);
      oa[jd] = __builtin_amdgcn_mfma_f32_16x16x32_bf16(pf1, vf1, oa[jd], 0, 0, 0);
    }
    __builtin_amdgcn_s_setprio(0);

    __syncthreads();  // all reads of cur done; next-chunk DMA drained
    cur ^= 1;
  }

#pragma unroll
  for (int r = 0; r < 4; ++r) {
    const int row = qt * 128 + w * 16 + g * 4 + r;
    const float inv = 1.0f / oa[4][r];
#pragma unroll
    for (int jd = 0; jd < 4; ++jd)
      out[((size_t)b * SS + row) * ED + h * 64 + jd * 16 + l15] =
          f2bf(oa[jd][r] * inv);
  }
}

// ---------------------------------------------------------------------------
// y = LN(ab + alpha*rb) over E=768; ab, rb bf16 (rb optional).
// Write fp32 (outf) and/or bf16 (outb).
// Wave-per-row: block = 256 = 4 waves = 4 rows; no LDS, no barriers.
// ---------------------------------------------------------------------------
__global__ __launch_bounds__(256) void add_ln(
    const ushort* __restrict__ ab, const ushort* __restrict__ rb, float alpha,
    const float* __restrict__ g, const float* __restrict__ bt,
    float* __restrict__ outf, ushort* __restrict__ outb) {
  const int row = blockIdx.x * 4 + (threadIdx.x >> 6);
  const int lane = threadIdx.x & 63;
  const size_t base = (size_t)row * ED;
  float4 x[3];
#pragma unroll
  for (int p = 0; p < 3; ++p) {
    const int idx = p * 256 + lane * 4;
    ushort4 u = *(const ushort4*)&ab[base + idx];
    x[p] = make_float4(bf2f(u.x), bf2f(u.y), bf2f(u.z), bf2f(u.w));
    if (rb) {
      ushort4 rv = *(const ushort4*)&rb[base + idx];
      x[p].x += alpha * bf2f(rv.x);
      x[p].y += alpha * bf2f(rv.y);
      x[p].z += alpha * bf2f(rv.z);
      x[p].w += alpha * bf2f(rv.w);
    }
  }
  float s = 0.f;
#pragma unroll
  for (int p = 0; p < 3; ++p) s += x[p].x + x[p].y + x[p].z + x[p].w;
  for (int off = 32; off; off >>= 1) s += __shfl_xor(s, off);
  const float mean = s * (1.0f / 768.0f);
  float v = 0.f;
#pragma unroll
  for (int p = 0; p < 3; ++p) {
    float d0 = x[p].x - mean, d1 = x[p].y - mean;
    float d2 = x[p].z - mean, d3 = x[p].w - mean;
    v += d0 * d0 + d1 * d1 + d2 * d2 + d3 * d3;
  }
  for (int off = 32; off; off >>= 1) v += __shfl_xor(v, off);
  const float rs = rsqrtf(v * (1.0f / 768.0f) + LN_EPS);
#pragma unroll
  for (int p = 0; p < 3; ++p) {
    const int idx = p * 256 + lane * 4;
    const float4 gv = *(const float4*)&g[idx];
    const float4 bb = *(const float4*)&bt[idx];
    const float y0 = (x[p].x - mean) * rs * gv.x + bb.x;
    const float y1 = (x[p].y - mean) * rs * gv.y + bb.y;
    const float y2 = (x[p].z - mean) * rs * gv.z + bb.z;
    const float y3 = (x[p].w - mean) * rs * gv.w + bb.w;
    if (outf) *(float4*)&outf[base + idx] = make_float4(y0, y1, y2, y3);
    if (outb)
      *(ushort4*)&outb[base + idx] =
          make_ushort4(f2bf(y0), f2bf(y1), f2bf(y2), f2bf(y3));
  }
}

// ---------------------------------------------------------------------------
extern "C" void kernel_launch(void* const* d_in, const int* in_sizes, int n_in,
                              void* d_out, int out_size, void* d_ws,
                              size_t ws_size, hipStream_t stream) {
  (void)in_sizes; (void)n_in; (void)out_size; (void)ws_size;
  const float* emb     = (const float*)d_in[0];
  const float* context = (const float*)d_in[1];
  const float* sa_wq = (const float*)d_in[2];
  const float* sa_wk = (const float*)d_in[3];
  const float* sa_wv = (const float*)d_in[4];
  const float* sa_wo = (const float*)d_in[5];
  const float* sa_wo_b = (const float*)d_in[6];
  const float* sa_qn_g = (const float*)d_in[7];
  const float* sa_qn_b = (const float*)d_in[8];
  const float* sa_kn_g = (const float*)d_in[9];
  const float* sa_kn_b = (const float*)d_in[10];
  const float* ca_wq = (const float*)d_in[11];
  const float* ca_wk = (const float*)d_in[12];
  const float* ca_wv = (const float*)d_in[13];
  const float* ca_wo = (const float*)d_in[14];
  const float* ca_wo_b = (const float*)d_in[15];
  const float* ca_qn_g = (const float*)d_in[16];
  const float* ca_qn_b = (const float*)d_in[17];
  const float* ca_kn_g = (const float*)d_in[18];
  const float* ca_kn_b = (const float*)d_in[19];
  const float* mlp_w1 = (const float*)d_in[20];
  const float* mlp_b1 = (const float*)d_in[21];
  const float* mlp_w2 = (const float*)d_in[22];
  const float* mlp_b2 = (const float*)d_in[23];
  const float* ln1_g = (const float*)d_in[24];
  const float* ln1_b = (const float*)d_in[25];
  const float* ln2_g = (const float*)d_in[26];
  const float* ln2_b = (const float*)d_in[27];
  const float* ln3_g = (const float*)d_in[28];
  const float* ln3_b = (const float*)d_in[29];
  float* out = (float*)d_out;

  // ---- workspace layout (106.2 MB) ----
  const size_t R = TOT_R;  // 6291456
  ushort* U = (ushort*)d_ws;
  ushort* Qh  = U;             // bf16 head tensors (V region holds V^T)
  ushort* Kh  = U + R;
  ushort* Vh  = U + 2 * R;
  ushort* SH1 = U + 3 * R;     // X1_bf (ln1 out: CAQ input + ln2 residual)
  ushort* SH2 = U + 4 * R;     // ctx_bf, then X2_bf, then M2b
  ushort* EB  = U + 5 * R;     // emb_bf (preserved: QKV input + ln1 residual)
  ushort* AO  = U + 6 * R;     // flash attention output (SA, then CA)
  ushort* WB  = U + 7 * R;     // transposed bf16 weights (9043968 elems)
  ushort* WOb = Qh;            // WO_sa / WO_ca bf16 out (Q dead post-flash)
  ushort* Hb  = Qh;            // MLP hidden [8192][3072] (spans Qh..SH1, dead)
  ushort* M2b = SH2;           // MLP2 bf16 out (SH2 dead after MLP1 reads it)

  // WB sub-offsets (bf16 elems)
  ushort* w_saqkv = WB;                      // [2304][768] (q|k|v)
  ushort* w_sao   = WB + 1769472;            // [768][768]
  ushort* w_caq   = WB + 2359296;            // [768][768]
  ushort* w_cakv  = WB + 2949120;            // [1536][512] (k|v)
  ushort* w_cao   = WB + 3735552;            // [768][768]
  ushort* w_m1    = WB + 4325376;            // [3072][768]
  ushort* w_m2    = WB + 6684672;            // [768][3072]

  dim3 blk(256);

  // ---- one fused conversion launch ----
  CvtPack P;
  const float* srcs[12] = {sa_wq, sa_wk, sa_wv, sa_wo, ca_wq, ca_wk, ca_wv,
                           ca_wo, mlp_w1, mlp_w2, emb, context};
  ushort* dsts[12] = {w_saqkv, w_saqkv + 589824, w_saqkv + 1179648, w_sao,
                      w_caq, w_cakv, w_cakv + 393216, w_cao, w_m1, w_m2,
                      EB, SH2};
  const int kds[12] = {ED, ED, ED, ED, ED, CD, CD, ED, ED, FD,
                       1572864, 262144};
  const int nds[12] = {ED, ED, ED, ED, ED, ED, ED, ED, FD, ED, 0, 0};
  int off = 0;
  for (int j = 0; j < 12; ++j) {
    P.src[j] = srcs[j]; P.dst[j] = dsts[j]; P.kd[j] = kds[j]; P.nd[j] = nds[j];
    P.off[j] = off;
    off += nds[j] ? (nds[j] >> 5) * (kds[j] >> 5) : (kds[j] + 255) >> 8;
  }
  P.off[12] = off;
  cvt_all<<<dim3(off), blk, 0, stream>>>(P);

  // ---- self-attention ----
  mfma_gemm<2><<<dim3(64, 18), blk, 0, stream>>>(
      EB, w_saqkv, nullptr, Qh, 8192, 2304, ED, 10,
      sa_qn_g, sa_qn_b, sa_kn_g, sa_kn_b, 0, 1, 2);
  flash_mfma<<<dim3(96, 8), dim3(512), 0, stream>>>(Qh, Kh, Vh, AO, SS);
  mfma_gemm<3><<<dim3(64, 6), blk, 0, stream>>>(
      AO, w_sao, sa_wo_b, WOb, 8192, ED, ED, 0,
      nullptr, nullptr, nullptr, nullptr, -1, -1, -1);
  add_ln<<<dim3(2048), blk, 0, stream>>>(WOb, EB, 2.0f, ln1_g, ln1_b,
                                         nullptr, SH1);

  // ---- cross-attention (Q and K/V projections fused in one dispatch) ----
  mfma_gemm_ca<<<dim3(576), blk, 0, stream>>>(
      SH1, w_caq, Qh, SH2, w_cakv, Kh,
      ca_qn_g, ca_qn_b, ca_kn_g, ca_kn_b);
  flash_mfma<<<dim3(96, 8), dim3(512), 0, stream>>>(Qh, Kh, Vh, AO, TT);
  mfma_gemm<3><<<dim3(64, 6), blk, 0, stream>>>(
      AO, w_cao, ca_wo_b, WOb, 8192, ED, ED, 0,
      nullptr, nullptr, nullptr, nullptr, -1, -1, -1);
  add_ln<<<dim3(2048), blk, 0, stream>>>(WOb, SH1, 1.0f, ln2_g, ln2_b,
                                         nullptr, SH2);

  // ---- MLP ----
  mfma_gemm<1><<<dim3(64, 24), blk, 0, stream>>>(
      SH2, w_m1, mlp_b1, Hb, 8192, FD, ED, 0,
      nullptr, nullptr, nullptr, nullptr, -1, -1, -1);
  mfma_gemm<3><<<dim3(64, 6), blk, 0, stream>>>(
      Hb, w_m2, mlp_b2, M2b, 8192, ED, FD, 0,
      nullptr, nullptr, nullptr, nullptr, -1, -1, -1);
  add_ln<<<dim3(2048), blk, 0, stream>>>(M2b, nullptr, 0.0f, ln3_g, ln3_b,
                                         out, nullptr);
}